// Round 11
// baseline (408.544 us; speedup 1.0000x reference)
//
#include <hip/hip_runtime.h>
#include <stdint.h>

// Transformer block: B=64 T=512 C=512 H=16 D=32, FF=2048. fp32 in/out, bf16 MFMA inside.

typedef __attribute__((ext_vector_type(8))) short bf16x8;
typedef __attribute__((ext_vector_type(4))) short bf16x4;
typedef __attribute__((ext_vector_type(4))) float f32x4;

__device__ __forceinline__ unsigned short f2bf(float x) {
  union { float f; unsigned u; } v; v.f = x;
  unsigned r = v.u + 0x7fff + ((v.u >> 16) & 1);   // RNE
  return (unsigned short)(r >> 16);
}

#if __has_builtin(__builtin_amdgcn_exp2f)
__device__ __forceinline__ float exp2fast(float x) { return __builtin_amdgcn_exp2f(x); }
#else
__device__ __forceinline__ float exp2fast(float x) { return exp2f(x); }
#endif

// v_cvt_pk_bf16_f32: lo -> bits[15:0], hi -> bits[31:16] (RNE). No builtin on gfx950.
__device__ __forceinline__ unsigned cvtpk(float lo, float hi) {
  unsigned r; asm("v_cvt_pk_bf16_f32 %0, %1, %2" : "=v"(r) : "v"(lo), "v"(hi)); return r;
}

__device__ __forceinline__ f32x4 MFMA32(bf16x8 a, bf16x8 b, f32x4 c) {
  return __builtin_amdgcn_mfma_f32_16x16x32_bf16(a, b, c, 0, 0, 0);
}

#if __has_builtin(__builtin_amdgcn_mfma_f32_16x16x16bf16_1k)
__device__ __forceinline__ f32x4 MFMA16(bf16x4 a, bf16x4 b, f32x4 c) {
  return __builtin_amdgcn_mfma_f32_16x16x16bf16_1k(a, b, c, 0, 0, 0);
}
#else
__device__ __forceinline__ f32x4 MFMA16(bf16x4 a, bf16x4 b, f32x4 c) {
  f32x4 d;
  asm volatile("v_mfma_f32_16x16x16_bf16 %0, %1, %2, %3\n\ts_nop 7\n\ts_nop 3"
               : "=v"(d) : "v"(a), "v"(b), "v"(c));
  return d;
}
#endif

// global -> LDS direct copy, 16B per lane. LDS dest must be wave-uniform base;
// HW writes base + lane*16. Global src is per-lane.
__device__ __forceinline__ void gload_lds16(const void* g, void* l) {
  __builtin_amdgcn_global_load_lds(
      (const __attribute__((address_space(1))) unsigned int*)(uintptr_t)g,
      (__attribute__((address_space(3))) unsigned int*)(unsigned)(uintptr_t)l,
      16, 0, 0);
}

#define WAITV0() do { asm volatile("s_waitcnt vmcnt(0)" ::: "memory"); } while (0)
#define SBAR()   __builtin_amdgcn_s_barrier()
#define SCHED0() __builtin_amdgcn_sched_barrier(0)

// ---------------- weight prep (LDS-tiled, coalesced both sides) ----------------
// dst[n][k] = W{q,k,v}[h][k][d], n = q*512 + h*32 + d. Block = (q,h,ktile of 64).
__global__ __launch_bounds__(256) void prep_qkv_w(
    const float* __restrict__ Wq, const float* __restrict__ Wk,
    const float* __restrict__ Wv, unsigned short* __restrict__ dst)
{
  __shared__ float tile[64 * 33];            // 64 k-rows x 32 d, pad 33
  const int b = blockIdx.x;                  // 3*16*8 = 384
  const int q = b / 128, hh = (b >> 3) & 15, kt = (b & 7) << 6;
  const float* W = (q == 0) ? Wq : ((q == 1) ? Wk : Wv);
  const int t = threadIdx.x;
  const int rr = t >> 2, ch = (t & 3) << 3;  // read: row, 8-float chunk
  const float* sp = W + ((size_t)hh * 512 + kt + rr) * 32 + ch;
  float4 v0 = *(const float4*)(sp), v1 = *(const float4*)(sp + 4);
  float* dp = &tile[rr * 33 + ch];
  dp[0] = v0.x; dp[1] = v0.y; dp[2] = v0.z; dp[3] = v0.w;
  dp[4] = v1.x; dp[5] = v1.y; dp[6] = v1.z; dp[7] = v1.w;
  __syncthreads();
  const int d = t >> 3, toct = (t & 7) << 3; // write: d-row, 8 k-elems
  bf16x8 o;
#pragma unroll
  for (int j = 0; j < 8; ++j) o[j] = (short)f2bf(tile[(toct + j) * 33 + d]);
  *(bf16x8*)(dst + ((size_t)q * 512 + hh * 32 + d) * 512 + kt + toct) = o;
}

// dst (Nd x Kd bf16) = transpose of src (Kd x Nd fp32). 64x64 tiles via LDS.
__global__ __launch_bounds__(256) void transpose_cast(
    const float* __restrict__ src, unsigned short* __restrict__ dst, int Kd, int Nd)
{
  __shared__ float tile[64 * 65];
  const int nk = Kd >> 6;
  const int kt = (blockIdx.x % nk) << 6, nt = (blockIdx.x / nk) << 6;
  const int t = threadIdx.x;
  const int rr = t >> 2, ch = (t & 3) << 4;  // read: k-row, 16-float chunk
  const float* sp = src + (size_t)(kt + rr) * Nd + nt + ch;
  float* dp = &tile[rr * 65 + ch];
#pragma unroll
  for (int c = 0; c < 4; ++c) {
    float4 v = *(const float4*)(sp + c * 4);
    dp[c * 4 + 0] = v.x; dp[c * 4 + 1] = v.y; dp[c * 4 + 2] = v.z; dp[c * 4 + 3] = v.w;
  }
  __syncthreads();
  const int nn = t >> 2, c2 = (t & 3) << 4;  // write: n-row, 16 k-elems
  bf16x8 o0, o1;
#pragma unroll
  for (int j = 0; j < 8; ++j) {
    o0[j] = (short)f2bf(tile[(c2 + j) * 65 + nn]);
    o1[j] = (short)f2bf(tile[(c2 + 8 + j) * 65 + nn]);
  }
  unsigned short* op = dst + (size_t)(nt + nn) * Kd + kt + c2;
  *(bf16x8*)(op) = o0;
  *(bf16x8*)(op + 8) = o1;
}

// ---------------- layernorm (fp32 in -> bf16 out), one wave per 512-row ----------------
__global__ __launch_bounds__(256) void ln_kernel(
    const float* __restrict__ x, const float* __restrict__ g,
    const float* __restrict__ b, unsigned short* __restrict__ out)
{
  const int lane = threadIdx.x & 63;
  const size_t row = (size_t)blockIdx.x * 4 + (threadIdx.x >> 6);
  const float* xp = x + row * 512 + lane * 8;
  float xv[8] __attribute__((aligned(16)));
  *(float4*)(xv)     = *(const float4*)(xp);
  *(float4*)(xv + 4) = *(const float4*)(xp + 4);
  float s = 0.f, s2 = 0.f;
#pragma unroll
  for (int j = 0; j < 8; ++j) { s += xv[j]; s2 += xv[j] * xv[j]; }
#pragma unroll
  for (int m = 1; m < 64; m <<= 1) { s += __shfl_xor(s, m); s2 += __shfl_xor(s2, m); }
  float mean = s * (1.f / 512.f);
  float rstd = rsqrtf(fmaxf(s2 * (1.f / 512.f) - mean * mean, 0.f) + 1e-5f);
  float gv[8] __attribute__((aligned(16))), bv[8] __attribute__((aligned(16)));
  *(float4*)(gv)     = *(const float4*)(g + lane * 8);
  *(float4*)(gv + 4) = *(const float4*)(g + lane * 8 + 4);
  *(float4*)(bv)     = *(const float4*)(b + lane * 8);
  *(float4*)(bv + 4) = *(const float4*)(b + lane * 8 + 4);
  bf16x8 o;
#pragma unroll
  for (int j = 0; j < 8; ++j) o[j] = (short)f2bf((xv[j] - mean) * rstd * gv[j] + bv[j]);
  *(bf16x8*)(out + row * 512 + lane * 8) = o;
}

// ---------------- V transpose: [B][H][T][D] -> [B][H][D][T], LDS-tiled ----------------
__global__ __launch_bounds__(256) void vt_kernel(
    const unsigned short* __restrict__ vnat, unsigned short* __restrict__ vt)
{
  __shared__ unsigned short tile[64 * 36];   // 64 t-rows x 32 d, padded to 36
  const int bh = blockIdx.x >> 3, tt = (blockIdx.x & 7) << 6;
  const int tid = threadIdx.x;
  const int rr = tid >> 2, ch = tid & 3;     // read: (t-row, 8-elem d-chunk)
  bf16x8 v = *(const bf16x8*)(vnat + ((size_t)bh * 512 + tt + rr) * 32 + ch * 8);
  unsigned short* dst = &tile[rr * 36 + ch * 8];
#pragma unroll
  for (int j = 0; j < 8; ++j) dst[j] = (unsigned short)v[j];
  __syncthreads();
  const int d = tid >> 3, toct = (tid & 7) << 3;  // write: (d-row, 8-elem t-chunk)
  union { unsigned short s[8]; bf16x8 v8; } o;
#pragma unroll
  for (int j = 0; j < 8; ++j) o.s[j] = tile[(toct + j) * 36 + d];
  *(bf16x8*)(vt + ((size_t)bh * 32 + d) * 512 + tt + toct) = o.v8;
}

// ---------------- persistent 256x256 GEMM, COMPILER-SCHEDULED K-loop -------
// Grid MUST be 256. 8 waves (2Mx4N), per-wave C 128x64; BK=64; 2 K-tile LDS dbuf.
// m97 mechanism: NO lgkm asm, NO sched pinning inside the loop — hipcc emits
// fine-grained lgkmcnt(N) between each ds_read and its consuming MFMA (m97 r109),
// which my r7-r10 hand lockstep (lgkmcnt(0)-before-cluster) defeated (m141 analog).
// Depth-1 issue-early prefetch: STAGE(g+1) into the dead buffer at the TOP of
// iteration g; the vmcnt(0) at the bottom is then nearly free (a full K-tile of
// compute has passed). One barrier per K-tile.
// Safety: every ds_read of tile g is consumed by an MFMA before the closing
// barrier (implicit lgkm drain); STAGE(g+1) writes the buffer whose readers
// finished one barrier earlier; buf visibility = own-wave vmcnt(0) + SBAR.
// MODE 1: QKV scatter (Q,K -> obf [2][B][H][T][D], Q scaled; V -> vout natural)
// MODE 2: out fp32 = acc + bias[col] + resid[row*N+col]
// MODE 3: out bf16 = relu(acc + bias[col])
template <int MODE, int P, int KT, int NBY>
__device__ __forceinline__ void gemm_persist(
    const unsigned short* __restrict__ A, const unsigned short* __restrict__ Bt,
    int N,
    unsigned short* __restrict__ obf, float* __restrict__ of32,
    const float* __restrict__ bias, const float* __restrict__ resid,
    unsigned short* __restrict__ vout)
{
  constexpr int K = KT * 64;
  constexpr int TOT = P * KT;
  __shared__ __align__(16) unsigned short As[2][256 * 64];
  __shared__ __align__(16) unsigned short Bs[2][256 * 64];
  const int tid = threadIdx.x, lane = tid & 63, wid = tid >> 6;
  const int wr = wid >> 2, wc = wid & 3;
  const int r = lane & 15, hq = lane >> 4;

  // XCD-chunked persistent tile list: block b -> tau0 = (b%8)*32P + (b/8)*P
  const int tau0 = (blockIdx.x & 7) * (32 * P) + (blockIdx.x >> 3) * P;

  const int srow = wid * 32 + (lane >> 3);
  const int schunk = ((lane & 7) ^ ((lane >> 3) & 7)) * 8;  // element offset in [0,64)

  auto STAGE_A = [&](int g2) {
    const int m2 = g2 / KT, kt2 = g2 % KT;
    const int bx = (tau0 + m2) / NBY;
    const unsigned short* src = A + (size_t)(bx * 256 + srow) * K + kt2 * 64 + schunk;
    char* dst = (char*)(&As[g2 & 1][0]) + wid * 4096;
#pragma unroll
    for (int g = 0; g < 4; ++g) gload_lds16(src + (size_t)g * 8 * K, dst + g * 1024);
  };
  auto STAGE_B = [&](int g2) {
    const int m2 = g2 / KT, kt2 = g2 % KT;
    const int tau = tau0 + m2;
    const int by = tau - (tau / NBY) * NBY;
    const unsigned short* src = Bt + (size_t)(by * 256 + srow) * K + kt2 * 64 + schunk;
    char* dst = (char*)(&Bs[g2 & 1][0]) + wid * 4096;
#pragma unroll
    for (int g = 0; g < 4; ++g) gload_lds16(src + (size_t)g * 8 * K, dst + g * 1024);
  };

  // ds_read addressing: byte = row*128 + ((chunk ^ (row&7))*16), chunk = kk*4+hq
  const int x0 = ((hq) ^ (r & 7)) * 16;
  const int x1 = ((4 + hq) ^ (r & 7)) * 16;
  const int abase = (wr * 128 + r) * 128;
  const int bbase = (wc * 64 + r) * 128;

  f32x4 acc[8][4] = {};

  STAGE_A(0); STAGE_B(0);
  WAITV0(); SCHED0();
  SBAR();

#pragma unroll 1
  for (int p = 0; p < P; ++p) {
#pragma unroll 2
    for (int t = 0; t < KT; ++t) {
      const int g = p * KT + t;
      // issue next tile's DMA first; it completes under this tile's compute
      if (g + 1 < TOT) { STAGE_A(g + 1); STAGE_B(g + 1); }
      const char* Ab = (const char*)(&As[g & 1][0]);
      const char* Bb = (const char*)(&Bs[g & 1][0]);
      // plain HIP reads + MFMAs: compiler interleaves with fine-grained lgkmcnt
      bf16x8 bf[4][2];
#pragma unroll
      for (int n = 0; n < 4; ++n) {
        bf[n][0] = *(const bf16x8*)(Bb + bbase + n * 2048 + x0);
        bf[n][1] = *(const bf16x8*)(Bb + bbase + n * 2048 + x1);
      }
#pragma unroll
      for (int m = 0; m < 8; ++m) {
        const bf16x8 a0 = *(const bf16x8*)(Ab + abase + m * 2048 + x0);
        const bf16x8 a1 = *(const bf16x8*)(Ab + abase + m * 2048 + x1);
#pragma unroll
        for (int n = 0; n < 4; ++n) {
          acc[m][n] = MFMA32(a0, bf[n][0], acc[m][n]);
          acc[m][n] = MFMA32(a1, bf[n][1], acc[m][n]);
        }
      }
      WAITV0(); SCHED0();   // nearly free: DMA issued one full K-tile ago
      SBAR();               // next buffer visible block-wide
    }

    // ---- macro epilogue (regs -> global only; next-macro DMA already in flight)
    {
      const int tau = tau0 + p;
      const int bx = tau / NBY, by = tau - bx * NBY;
      const int brow = bx << 8, bcol = by << 8;
#pragma unroll
      for (int m = 0; m < 8; ++m)
#pragma unroll
        for (int n = 0; n < 4; ++n) {
          const int row0 = brow + wr * 128 + m * 16 + hq * 4;
          const int col = bcol + wc * 64 + n * 16 + r;
#pragma unroll
          for (int q2 = 0; q2 < 4; ++q2) {
            const int row = row0 + q2;
            float v = acc[m][n][q2];
            if (MODE == 1) {
              const int which = col >> 9, hh = (col >> 5) & 15, dd = col & 31;
              const int bb = row >> 9, tt = row & 511;
              const size_t off = ((((size_t)bb) * 16 + hh) * 512 + tt) * 32 + dd;
              if (which < 2) {
                if (which == 0) v *= 0.25503521f;  // (1/sqrt(32)) * log2(e)
                obf[(size_t)which * 16777216 + off] = f2bf(v);
              } else
                vout[off] = f2bf(v);
            } else if (MODE == 2) {
              v += bias[col] + resid[(size_t)row * N + col];
              of32[(size_t)row * N + col] = v;
            } else if (MODE == 3) {
              v = fmaxf(v + bias[col], 0.f);
              obf[(size_t)row * N + col] = f2bf(v);
            }
            acc[m][n][q2] = 0.f;
          }
        }
    }
  }
}

// distinct names per call site for rocprof attribution; grid must be 256
__global__ __launch_bounds__(512, 2) void qkv_gemm(
    const unsigned short* __restrict__ A, const unsigned short* __restrict__ Bt,
    unsigned short* __restrict__ obf, unsigned short* __restrict__ vout)
{ gemm_persist<1, 3, 8, 6>(A, Bt, 1536, obf, nullptr, nullptr, nullptr, vout); }

__global__ __launch_bounds__(512, 2) void proj_gemm(
    const unsigned short* __restrict__ A, const unsigned short* __restrict__ Bt,
    float* __restrict__ of32, const float* __restrict__ bias,
    const float* __restrict__ resid)
{ gemm_persist<2, 1, 8, 2>(A, Bt, 512, nullptr, of32, bias, resid, nullptr); }

__global__ __launch_bounds__(512, 2) void ffn1_gemm(
    const unsigned short* __restrict__ A, const unsigned short* __restrict__ Bt,
    unsigned short* __restrict__ obf, const float* __restrict__ bias)
{ gemm_persist<3, 4, 8, 8>(A, Bt, 2048, obf, nullptr, bias, nullptr, nullptr); }

__global__ __launch_bounds__(512, 2) void ffn2_gemm(
    const unsigned short* __restrict__ A, const unsigned short* __restrict__ Bt,
    float* __restrict__ of32, const float* __restrict__ bias,
    const float* __restrict__ resid)
{ gemm_persist<2, 1, 32, 2>(A, Bt, 512, nullptr, of32, bias, resid, nullptr); }

// ---------------- causal attention: one block per (b,h), 8 waves ----------------
// Swapped QK^T: S^T = mfma(K_frag, Q_frag) so each lane owns one q-column with
// keys lane-local (k = 4*hq + j per 16-key tile). Softmax: in-lane tree + 2 shfl_xor.
// P feeds PV (16x16x16 MFMA) directly via cvt_pk -> no LDS round-trip.
// Scores arrive pre-scaled by (1/sqrt(32))*log2(e); exp = v_exp_f32 (2^x).
// Qb,Kb: [B][H][T][D] bf16 ; Vt: [B][H][D][T] bf16 ; att: [B*T][512] bf16 (col h*32+d)
__global__ __launch_bounds__(512, 4) void attn_kernel(
    const unsigned short* __restrict__ Qb, const unsigned short* __restrict__ Kb,
    const unsigned short* __restrict__ Vt, unsigned short* __restrict__ att)
{
  __shared__ __align__(16) unsigned short Ks[512 * 32];  // 32 KB, linear [t][d]
  __shared__ __align__(16) unsigned short Vs[32 * 512];  // 32 KB, [d][t], 16B-blk ^ (d&15)
  const int tid = threadIdx.x, lane = tid & 63, wid = tid >> 6;
  const int bh = blockIdx.x;
  const int r = lane & 15, hq = lane >> 4;
  const unsigned short* Kg = Kb + (size_t)bh * (512 * 32);
  const unsigned short* Vg = Vt + (size_t)bh * (32 * 512);
#pragma unroll
  for (int it = 0; it < 4; ++it) {
    const int c = it * 512 + tid;
    gload_lds16(Kg + c * 8, (char*)Ks + (it * 512 + wid * 64) * 16);
    const int d = c >> 6, sb = c & 63;
    gload_lds16(Vg + d * 512 + (sb ^ (d & 15)) * 8, (char*)Vs + (it * 512 + wid * 64) * 16);
  }
  __syncthreads();

  const f32x4 z = {0.f, 0.f, 0.f, 0.f};
  for (int p = 0; p < 4; ++p) {
    // balanced triangular tile pairing: waves get tiles {w, 15-w, 16+w, 31-w}
    const int t0 = (((p >> 1) << 4) + ((p & 1) ? 15 - wid : wid)) << 4;
    const bf16x8 qf = *(const bf16x8*)(Qb + ((size_t)bh * 512 + t0 + r) * 32 + hq * 8);
    f32x4 o0 = z, o1 = z;
    float m = -1e30f, l = 0.f;
    const int s0m = t0 & ~31;
    for (int s0 = 0; s0 <= s0m; s0 += 32) {
      f32x4 st0 = MFMA32(*(const bf16x8*)((const char*)Ks + (s0 + r) * 64 + hq * 16), qf, z);
      f32x4 st1 = MFMA32(*(const bf16x8*)((const char*)Ks + (s0 + 16 + r) * 64 + hq * 16), qf, z);
      if (s0 == s0m) {                       // only the diagonal chunk needs masking
        const int qq = t0 + r;
#pragma unroll
        for (int j = 0; j < 4; ++j) {
          if (s0 + 4 * hq + j > qq)      st0[j] = -1e30f;
          if (s0 + 16 + 4 * hq + j > qq) st1[j] = -1e30f;
        }
      }
      float mx = fmaxf(fmaxf(fmaxf(st0[0], st0[1]), fmaxf(st0[2], st0[3])),
                       fmaxf(fmaxf(st1[0], st1[1]), fmaxf(st1[2], st1[3])));
      mx = fmaxf(mx, __shfl_xor(mx, 16));
      mx = fmaxf(mx, __shfl_xor(mx, 32));
      if (!__all(mx <= m + 8.f)) {           // defer-max (T13), THR=8 in log2 domain
        const float mn = fmaxf(m, mx);
        const float f = exp2fast(m - mn);
        m = mn; l *= f; o0 *= f; o1 *= f;
      }
      float p0[4], p1[4];
#pragma unroll
      for (int j = 0; j < 4; ++j) {
        p0[j] = exp2fast(st0[j] - m);
        p1[j] = exp2fast(st1[j] - m);
      }
      float rs = ((p0[0] + p0[1]) + (p0[2] + p0[3])) + ((p1[0] + p1[1]) + (p1[2] + p1[3]));
      rs += __shfl_xor(rs, 16);
      rs += __shfl_xor(rs, 32);
      l += rs;
      union { unsigned u[2]; bf16x4 v; } a0, a1;
      a0.u[0] = cvtpk(p0[0], p0[1]); a0.u[1] = cvtpk(p0[2], p0[3]);
      a1.u[0] = cvtpk(p1[0], p1[1]); a1.u[1] = cvtpk(p1[2], p1[3]);
      const int lb = (s0 >> 3) + (hq >> 1);
      const char* vb = (const char*)Vs + (hq & 1) * 8;
      o0 = MFMA16(a0.v, *(const bf16x4*)(vb + r * 1024 + ((lb) ^ r) * 16), o0);
      o0 = MFMA16(a1.v, *(const bf16x4*)(vb + r * 1024 + ((lb + 2) ^ r) * 16), o0);
      o1 = MFMA16(a0.v, *(const bf16x4*)(vb + (r + 16) * 1024 + ((lb) ^ r) * 16), o1);
      o1 = MFMA16(a1.v, *(const bf16x4*)(vb + (r + 16) * 1024 + ((lb + 2) ^ r) * 16), o1);
    }
    // O ownership: d = r (o0) / 16+r (o1), q = t0 + 4*hq + j. l lives on lanes keyed by
    // r == q_rel (all 4 hq copies equal after the xor-reduce) -> shfl to fetch.
    const size_t ob = ((size_t)(bh >> 4) * 512) * 512 + (size_t)((bh & 15) * 32);
#pragma unroll
    for (int j = 0; j < 4; ++j) {
      const float li = 1.f / __shfl(l, 4 * hq + j);
      const size_t rowb = ob + (size_t)(t0 + 4 * hq + j) * 512;
      att[rowb + r]      = f2bf(o0[j] * li);
      att[rowb + 16 + r] = f2bf(o1[j] * li);
    }
  }
}

// ---------------- launcher ----------------
extern "C" void kernel_launch(void* const* d_in, const int* in_sizes, int n_in,
                              void* d_out, int out_size, void* d_ws, size_t ws_size,
                              hipStream_t stream)
{
  const float* x   = (const float*)d_in[0];
  const float* Wq  = (const float*)d_in[1];
  const float* Wk  = (const float*)d_in[2];
  const float* Wv  = (const float*)d_in[3];
  const float* Wp  = (const float*)d_in[4];
  const float* bp  = (const float*)d_in[5];
  const float* W1  = (const float*)d_in[6];
  const float* b1  = (const float*)d_in[7];
  const float* W2  = (const float*)d_in[8];
  const float* b2  = (const float*)d_in[9];
  const float* g1  = (const float*)d_in[10];
  const float* bb1 = (const float*)d_in[11];
  const float* g2  = (const float*)d_in[12];
  const float* bb2 = (const float*)d_in[13];
  float* out = (float*)d_out;

  char* ws = (char*)d_ws;
  // layout (bytes):
  unsigned short* h    = (unsigned short*)(ws);               // 32 MB (h, then reused as h2)
  unsigned short* wqkv = (unsigned short*)(ws + 33554432);    // 1.5 MB (1536 x 512)
  unsigned short* wp   = (unsigned short*)(ws + 35127296);    // 0.5 MB (512 x 512)
  unsigned short* w1   = (unsigned short*)(ws + 35651584);    // 2 MB (2048 x 512)
  unsigned short* w2   = (unsigned short*)(ws + 37748736);    // 2 MB (512 x 2048)
  unsigned short* qk   = (unsigned short*)(ws + 39845888);    // 64 MB: Q then K [B][H][T][D]
  unsigned short* vt   = qk + (size_t)2 * 16777216;           // 32 MB: V^T [B][H][D][T]
  unsigned short* att  = vt + 16777216;                       // 32 MB: attn out / V-natural
  unsigned short* vnat = att;                                 // V [B][H][T][D] staging
  unsigned short* mid  = qk;                                  // 128 MB alias over qk+vt+att
  if (ws_size < 174063616) return;  // insufficient workspace -> visible failure

  prep_qkv_w<<<384, 256, 0, stream>>>(Wq, Wk, Wv, wqkv);
  transpose_cast<<<64, 256, 0, stream>>>(Wp, wp, 512, 512);
  transpose_cast<<<256, 256, 0, stream>>>(W1, w1, 512, 2048);
  transpose_cast<<<256, 256, 0, stream>>>(W2, w2, 2048, 512);

  ln_kernel<<<8192, 256, 0, stream>>>(x, g1, bb1, h);

  qkv_gemm<<<256, 512, 0, stream>>>(h, wqkv, qk, vnat);

  vt_kernel<<<8192, 256, 0, stream>>>(vnat, vt);

  attn_kernel<<<1024, 512, 0, stream>>>(qk, qk + 16777216, vt, att);

  proj_gemm<<<256, 512, 0, stream>>>(att, wp, out, bp, x);

  ln_kernel<<<8192, 256, 0, stream>>>(out, g2, bb2, h);

  ffn1_gemm<<<256, 512, 0, stream>>>(h, w1, mid, b1);

  ffn2_gemm<<<256, 512, 0, stream>>>(mid, w2, out, b2, out);
}

// Round 12
// 380.348 us; speedup vs baseline: 1.0741x; 1.0741x over previous
//
#include <hip/hip_runtime.h>
#include <stdint.h>

// Transformer block: B=64 T=512 C=512 H=16 D=32, FF=2048. fp32 in/out, bf16 MFMA inside.

typedef __attribute__((ext_vector_type(8))) short bf16x8;
typedef __attribute__((ext_vector_type(4))) short bf16x4;
typedef __attribute__((ext_vector_type(4))) float f32x4;

__device__ __forceinline__ unsigned short f2bf(float x) {
  union { float f; unsigned u; } v; v.f = x;
  unsigned r = v.u + 0x7fff + ((v.u >> 16) & 1);   // RNE
  return (unsigned short)(r >> 16);
}

#if __has_builtin(__builtin_amdgcn_exp2f)
__device__ __forceinline__ float exp2fast(float x) { return __builtin_amdgcn_exp2f(x); }
#else
__device__ __forceinline__ float exp2fast(float x) { return exp2f(x); }
#endif

// v_cvt_pk_bf16_f32: lo -> bits[15:0], hi -> bits[31:16] (RNE). No builtin on gfx950.
__device__ __forceinline__ unsigned cvtpk(float lo, float hi) {
  unsigned r; asm("v_cvt_pk_bf16_f32 %0, %1, %2" : "=v"(r) : "v"(lo), "v"(hi)); return r;
}

__device__ __forceinline__ f32x4 MFMA32(bf16x8 a, bf16x8 b, f32x4 c) {
  return __builtin_amdgcn_mfma_f32_16x16x32_bf16(a, b, c, 0, 0, 0);
}

#if __has_builtin(__builtin_amdgcn_mfma_f32_16x16x16bf16_1k)
__device__ __forceinline__ f32x4 MFMA16(bf16x4 a, bf16x4 b, f32x4 c) {
  return __builtin_amdgcn_mfma_f32_16x16x16bf16_1k(a, b, c, 0, 0, 0);
}
#else
__device__ __forceinline__ f32x4 MFMA16(bf16x4 a, bf16x4 b, f32x4 c) {
  f32x4 d;
  asm volatile("v_mfma_f32_16x16x16_bf16 %0, %1, %2, %3\n\ts_nop 7\n\ts_nop 3"
               : "=v"(d) : "v"(a), "v"(b), "v"(c));
  return d;
}
#endif

// global -> LDS direct copy, 16B per lane. LDS dest must be wave-uniform base;
// HW writes base + lane*16. Global src is per-lane.
__device__ __forceinline__ void gload_lds16(const void* g, void* l) {
  __builtin_amdgcn_global_load_lds(
      (const __attribute__((address_space(1))) unsigned int*)(uintptr_t)g,
      (__attribute__((address_space(3))) unsigned int*)(unsigned)(uintptr_t)l,
      16, 0, 0);
}

// ---------------- weight prep (LDS-tiled, coalesced both sides) ----------------
// dst[n][k] = W{q,k,v}[h][k][d], n = q*512 + h*32 + d. Block = (q,h,ktile of 64).
__global__ __launch_bounds__(256) void prep_qkv_w(
    const float* __restrict__ Wq, const float* __restrict__ Wk,
    const float* __restrict__ Wv, unsigned short* __restrict__ dst)
{
  __shared__ float tile[64 * 33];            // 64 k-rows x 32 d, pad 33
  const int b = blockIdx.x;                  // 3*16*8 = 384
  const int q = b / 128, hh = (b >> 3) & 15, kt = (b & 7) << 6;
  const float* W = (q == 0) ? Wq : ((q == 1) ? Wk : Wv);
  const int t = threadIdx.x;
  const int rr = t >> 2, ch = (t & 3) << 3;  // read: row, 8-float chunk
  const float* sp = W + ((size_t)hh * 512 + kt + rr) * 32 + ch;
  float4 v0 = *(const float4*)(sp), v1 = *(const float4*)(sp + 4);
  float* dp = &tile[rr * 33 + ch];
  dp[0] = v0.x; dp[1] = v0.y; dp[2] = v0.z; dp[3] = v0.w;
  dp[4] = v1.x; dp[5] = v1.y; dp[6] = v1.z; dp[7] = v1.w;
  __syncthreads();
  const int d = t >> 3, toct = (t & 7) << 3; // write: d-row, 8 k-elems
  bf16x8 o;
#pragma unroll
  for (int j = 0; j < 8; ++j) o[j] = (short)f2bf(tile[(toct + j) * 33 + d]);
  *(bf16x8*)(dst + ((size_t)q * 512 + hh * 32 + d) * 512 + kt + toct) = o;
}

// dst (Nd x Kd bf16) = transpose of src (Kd x Nd fp32). 64x64 tiles via LDS.
__global__ __launch_bounds__(256) void transpose_cast(
    const float* __restrict__ src, unsigned short* __restrict__ dst, int Kd, int Nd)
{
  __shared__ float tile[64 * 65];
  const int nk = Kd >> 6;
  const int kt = (blockIdx.x % nk) << 6, nt = (blockIdx.x / nk) << 6;
  const int t = threadIdx.x;
  const int rr = t >> 2, ch = (t & 3) << 4;  // read: k-row, 16-float chunk
  const float* sp = src + (size_t)(kt + rr) * Nd + nt + ch;
  float* dp = &tile[rr * 65 + ch];
#pragma unroll
  for (int c = 0; c < 4; ++c) {
    float4 v = *(const float4*)(sp + c * 4);
    dp[c * 4 + 0] = v.x; dp[c * 4 + 1] = v.y; dp[c * 4 + 2] = v.z; dp[c * 4 + 3] = v.w;
  }
  __syncthreads();
  const int nn = t >> 2, c2 = (t & 3) << 4;  // write: n-row, 16 k-elems
  bf16x8 o0, o1;
#pragma unroll
  for (int j = 0; j < 8; ++j) {
    o0[j] = (short)f2bf(tile[(c2 + j) * 65 + nn]);
    o1[j] = (short)f2bf(tile[(c2 + 8 + j) * 65 + nn]);
  }
  unsigned short* op = dst + (size_t)(nt + nn) * Kd + kt + c2;
  *(bf16x8*)(op) = o0;
  *(bf16x8*)(op + 8) = o1;
}

// ---------------- layernorm (fp32 in -> bf16 out), one wave per 512-row ----------------
__global__ __launch_bounds__(256) void ln_kernel(
    const float* __restrict__ x, const float* __restrict__ g,
    const float* __restrict__ b, unsigned short* __restrict__ out)
{
  const int lane = threadIdx.x & 63;
  const size_t row = (size_t)blockIdx.x * 4 + (threadIdx.x >> 6);
  const float* xp = x + row * 512 + lane * 8;
  float xv[8] __attribute__((aligned(16)));
  *(float4*)(xv)     = *(const float4*)(xp);
  *(float4*)(xv + 4) = *(const float4*)(xp + 4);
  float s = 0.f, s2 = 0.f;
#pragma unroll
  for (int j = 0; j < 8; ++j) { s += xv[j]; s2 += xv[j] * xv[j]; }
#pragma unroll
  for (int m = 1; m < 64; m <<= 1) { s += __shfl_xor(s, m); s2 += __shfl_xor(s2, m); }
  float mean = s * (1.f / 512.f);
  float rstd = rsqrtf(fmaxf(s2 * (1.f / 512.f) - mean * mean, 0.f) + 1e-5f);
  float gv[8] __attribute__((aligned(16))), bv[8] __attribute__((aligned(16)));
  *(float4*)(gv)     = *(const float4*)(g + lane * 8);
  *(float4*)(gv + 4) = *(const float4*)(g + lane * 8 + 4);
  *(float4*)(bv)     = *(const float4*)(b + lane * 8);
  *(float4*)(bv + 4) = *(const float4*)(b + lane * 8 + 4);
  bf16x8 o;
#pragma unroll
  for (int j = 0; j < 8; ++j) o[j] = (short)f2bf((xv[j] - mean) * rstd * gv[j] + bv[j]);
  *(bf16x8*)(out + row * 512 + lane * 8) = o;
}

// ---------------- V transpose: [B][H][T][D] -> [B][H][D][T], LDS-tiled ----------------
__global__ __launch_bounds__(256) void vt_kernel(
    const unsigned short* __restrict__ vnat, unsigned short* __restrict__ vt)
{
  __shared__ unsigned short tile[64 * 36];   // 64 t-rows x 32 d, padded to 36
  const int bh = blockIdx.x >> 3, tt = (blockIdx.x & 7) << 6;
  const int tid = threadIdx.x;
  const int rr = tid >> 2, ch = tid & 3;     // read: (t-row, 8-elem d-chunk)
  bf16x8 v = *(const bf16x8*)(vnat + ((size_t)bh * 512 + tt + rr) * 32 + ch * 8);
  unsigned short* dst = &tile[rr * 36 + ch * 8];
#pragma unroll
  for (int j = 0; j < 8; ++j) dst[j] = (unsigned short)v[j];
  __syncthreads();
  const int d = tid >> 3, toct = (tid & 7) << 3;  // write: (d-row, 8-elem t-chunk)
  union { unsigned short s[8]; bf16x8 v8; } o;
#pragma unroll
  for (int j = 0; j < 8; ++j) o.s[j] = tile[(toct + j) * 36 + d];
  *(bf16x8*)(vt + ((size_t)bh * 32 + d) * 512 + tt + toct) = o.v8;
}

// ---------------- m97-structure 128x128 GEMM: C = A(MxK,bf16) * Bt(NxK,bf16)^T -----
// 4 waves (2x2), per-wave C 64x64, BK=64, SINGLE-buffered 32KB LDS -> ~3 blocks/CU.
// TLP replaces intra-block pipelining (m114: independent blocks co-schedule MFMA and
// staging; the r3-r11 256^2 1-block/CU lockstep could not hide any stall).
// Loop: STAGE(t) -> __syncthreads (compiler drains vmcnt) -> ds_reads + 32 MFMA/wave
// -> __syncthreads. No manual waits, no setprio, no sched pinning (m141 lesson).
// 16B-chunk XOR swizzle on global src + same XOR on ds_read (G21); 0 bank conflicts.
// MODE 1: QKV scatter (Q,K -> obf [2][B][H][T][D], Q scaled; V -> vout natural)
// MODE 2: out fp32 = acc + bias[col] + resid[row*N+col]
// MODE 3: out bf16 = relu(acc + bias[col])
template <int MODE>
__device__ __forceinline__ void gemm128_body(
    const unsigned short* __restrict__ A, const unsigned short* __restrict__ Bt,
    int N, int K, int nby,
    unsigned short* __restrict__ obf, float* __restrict__ of32,
    const float* __restrict__ bias, const float* __restrict__ resid,
    unsigned short* __restrict__ vout)
{
  __shared__ __align__(16) unsigned short As[128 * 64];
  __shared__ __align__(16) unsigned short Bs[128 * 64];
  const int tid = threadIdx.x, lane = tid & 63, wid = tid >> 6;  // 4 waves
  const int wr = wid >> 1, wc = wid & 1;
  const int r = lane & 15, hq = lane >> 4;

  // XCD-aware bijective swizzle (all grids % 8 == 0), row-major decode
  const int qq = gridDim.x >> 3;
  const int swz = (blockIdx.x & 7) * qq + (blockIdx.x >> 3);
  const int bx = swz / nby, by = swz - bx * nby;
  const int brow = bx << 7, bcol = by << 7;
  const int nkt = K >> 6;

  // staging: gload round g covers rows [g*32, g*32+32); wave w owns rows g*32+w*8..+8.
  // lane l -> row + (l>>3), LDS chunk l&7 (linear); global chunk pre-swizzled.
  const int srow = wid * 8 + (lane >> 3);
  const int schunk = ((lane & 7) ^ ((lane >> 3) & 7)) * 8;
  const unsigned short* Abase = A + (size_t)(brow + srow) * K + schunk;
  const unsigned short* Bbase = Bt + (size_t)(bcol + srow) * K + schunk;

  // ds_read addressing: byte = row*128 + ((chunk ^ (row&7))*16), chunk = kk*4+hq
  const int x0 = (hq ^ (r & 7)) * 16;
  const int x1 = ((4 + hq) ^ (r & 7)) * 16;
  const int abase = (wr * 64 + r) * 128;
  const int bbase = (wc * 64 + r) * 128;

  f32x4 acc[4][4] = {};

  for (int t = 0; t < nkt; ++t) {
    // ---- stage tile t into the single buffer (4 rounds of 32 rows each, A and B)
    {
      const unsigned short* as_ = Abase + t * 64;
      const unsigned short* bs_ = Bbase + t * 64;
      char* al_ = (char*)As + wid * 1024;
      char* bl_ = (char*)Bs + wid * 1024;
#pragma unroll
      for (int g = 0; g < 4; ++g) {
        gload_lds16(as_ + (size_t)g * 32 * K, al_ + g * 4096);
        gload_lds16(bs_ + (size_t)g * 32 * K, bl_ + g * 4096);
      }
    }
    __syncthreads();   // compiler emits vmcnt(0) drain before s_barrier
    // ---- compute: compiler interleaves ds_reads and MFMAs with fine-grained lgkmcnt
    bf16x8 bf[4][2];
#pragma unroll
    for (int n = 0; n < 4; ++n) {
      bf[n][0] = *(const bf16x8*)((const char*)Bs + bbase + n * 2048 + x0);
      bf[n][1] = *(const bf16x8*)((const char*)Bs + bbase + n * 2048 + x1);
    }
#pragma unroll
    for (int m = 0; m < 4; ++m) {
      const bf16x8 a0 = *(const bf16x8*)((const char*)As + abase + m * 2048 + x0);
      const bf16x8 a1 = *(const bf16x8*)((const char*)As + abase + m * 2048 + x1);
#pragma unroll
      for (int n = 0; n < 4; ++n) {
        acc[m][n] = MFMA32(a0, bf[n][0], acc[m][n]);
        acc[m][n] = MFMA32(a1, bf[n][1], acc[m][n]);
      }
    }
    __syncthreads();   // all reads of tile t done before next stage overwrites
  }

  // ---- epilogue: row = brow + wr*64 + m*16 + hq*4 + q2, col = bcol + wc*64 + n*16 + r
#pragma unroll
  for (int m = 0; m < 4; ++m)
#pragma unroll
    for (int n = 0; n < 4; ++n) {
      const int row0 = brow + wr * 64 + m * 16 + hq * 4;
      const int col = bcol + wc * 64 + n * 16 + r;
#pragma unroll
      for (int q2 = 0; q2 < 4; ++q2) {
        const int row = row0 + q2;
        float v = acc[m][n][q2];
        if (MODE == 1) {
          const int which = col >> 9, hh = (col >> 5) & 15, dd = col & 31;
          const int bb = row >> 9, tt = row & 511;
          const size_t off = ((((size_t)bb) * 16 + hh) * 512 + tt) * 32 + dd;
          if (which < 2) {
            if (which == 0) v *= 0.25503521f;  // (1/sqrt(32)) * log2(e)
            obf[(size_t)which * 16777216 + off] = f2bf(v);
          } else
            vout[off] = f2bf(v);
        } else if (MODE == 2) {
          v += bias[col] + resid[(size_t)row * N + col];
          of32[(size_t)row * N + col] = v;
        } else if (MODE == 3) {
          v = fmaxf(v + bias[col], 0.f);
          obf[(size_t)row * N + col] = f2bf(v);
        }
      }
    }
}

// distinct names per call site for rocprof attribution
__global__ __launch_bounds__(256, 3) void qkv_gemm(
    const unsigned short* __restrict__ A, const unsigned short* __restrict__ Bt,
    int N, int K, int nby, unsigned short* __restrict__ obf,
    unsigned short* __restrict__ vout)
{ gemm128_body<1>(A, Bt, N, K, nby, obf, nullptr, nullptr, nullptr, vout); }

__global__ __launch_bounds__(256, 3) void proj_gemm(
    const unsigned short* __restrict__ A, const unsigned short* __restrict__ Bt,
    int N, int K, int nby, float* __restrict__ of32,
    const float* __restrict__ bias, const float* __restrict__ resid)
{ gemm128_body<2>(A, Bt, N, K, nby, nullptr, of32, bias, resid, nullptr); }

__global__ __launch_bounds__(256, 3) void ffn1_gemm(
    const unsigned short* __restrict__ A, const unsigned short* __restrict__ Bt,
    int N, int K, int nby, unsigned short* __restrict__ obf,
    const float* __restrict__ bias)
{ gemm128_body<3>(A, Bt, N, K, nby, obf, nullptr, bias, nullptr, nullptr); }

__global__ __launch_bounds__(256, 3) void ffn2_gemm(
    const unsigned short* __restrict__ A, const unsigned short* __restrict__ Bt,
    int N, int K, int nby, float* __restrict__ of32,
    const float* __restrict__ bias, const float* __restrict__ resid)
{ gemm128_body<2>(A, Bt, N, K, nby, nullptr, of32, bias, resid, nullptr); }

// ---------------- causal attention: one block per (b,h), 8 waves ----------------
// Swapped QK^T: S^T = mfma(K_frag, Q_frag) so each lane owns one q-column with
// keys lane-local (k = 4*hq + j per 16-key tile). Softmax: in-lane tree + 2 shfl_xor.
// P feeds PV (16x16x16 MFMA) directly via cvt_pk -> no LDS round-trip.
// Scores arrive pre-scaled by (1/sqrt(32))*log2(e); exp = v_exp_f32 (2^x).
// Qb,Kb: [B][H][T][D] bf16 ; Vt: [B][H][D][T] bf16 ; att: [B*T][512] bf16 (col h*32+d)
__global__ __launch_bounds__(512, 4) void attn_kernel(
    const unsigned short* __restrict__ Qb, const unsigned short* __restrict__ Kb,
    const unsigned short* __restrict__ Vt, unsigned short* __restrict__ att)
{
  __shared__ __align__(16) unsigned short Ks[512 * 32];  // 32 KB, linear [t][d]
  __shared__ __align__(16) unsigned short Vs[32 * 512];  // 32 KB, [d][t], 16B-blk ^ (d&15)
  const int tid = threadIdx.x, lane = tid & 63, wid = tid >> 6;
  const int bh = blockIdx.x;
  const int r = lane & 15, hq = lane >> 4;
  const unsigned short* Kg = Kb + (size_t)bh * (512 * 32);
  const unsigned short* Vg = Vt + (size_t)bh * (32 * 512);
#pragma unroll
  for (int it = 0; it < 4; ++it) {
    const int c = it * 512 + tid;
    gload_lds16(Kg + c * 8, (char*)Ks + (it * 512 + wid * 64) * 16);
    const int d = c >> 6, sb = c & 63;
    gload_lds16(Vg + d * 512 + (sb ^ (d & 15)) * 8, (char*)Vs + (it * 512 + wid * 64) * 16);
  }
  __syncthreads();

  const f32x4 z = {0.f, 0.f, 0.f, 0.f};
  for (int p = 0; p < 4; ++p) {
    // balanced triangular tile pairing: waves get tiles {w, 15-w, 16+w, 31-w}
    const int t0 = (((p >> 1) << 4) + ((p & 1) ? 15 - wid : wid)) << 4;
    const bf16x8 qf = *(const bf16x8*)(Qb + ((size_t)bh * 512 + t0 + r) * 32 + hq * 8);
    f32x4 o0 = z, o1 = z;
    float m = -1e30f, l = 0.f;
    const int s0m = t0 & ~31;
    for (int s0 = 0; s0 <= s0m; s0 += 32) {
      f32x4 st0 = MFMA32(*(const bf16x8*)((const char*)Ks + (s0 + r) * 64 + hq * 16), qf, z);
      f32x4 st1 = MFMA32(*(const bf16x8*)((const char*)Ks + (s0 + 16 + r) * 64 + hq * 16), qf, z);
      if (s0 == s0m) {                       // only the diagonal chunk needs masking
        const int qq = t0 + r;
#pragma unroll
        for (int j = 0; j < 4; ++j) {
          if (s0 + 4 * hq + j > qq)      st0[j] = -1e30f;
          if (s0 + 16 + 4 * hq + j > qq) st1[j] = -1e30f;
        }
      }
      float mx = fmaxf(fmaxf(fmaxf(st0[0], st0[1]), fmaxf(st0[2], st0[3])),
                       fmaxf(fmaxf(st1[0], st1[1]), fmaxf(st1[2], st1[3])));
      mx = fmaxf(mx, __shfl_xor(mx, 16));
      mx = fmaxf(mx, __shfl_xor(mx, 32));
      if (!__all(mx <= m + 8.f)) {           // defer-max (T13), THR=8 in log2 domain
        const float mn = fmaxf(m, mx);
        const float f = exp2fast(m - mn);
        m = mn; l *= f; o0 *= f; o1 *= f;
      }
      float p0[4], p1[4];
#pragma unroll
      for (int j = 0; j < 4; ++j) {
        p0[j] = exp2fast(st0[j] - m);
        p1[j] = exp2fast(st1[j] - m);
      }
      float rs = ((p0[0] + p0[1]) + (p0[2] + p0[3])) + ((p1[0] + p1[1]) + (p1[2] + p1[3]));
      rs += __shfl_xor(rs, 16);
      rs += __shfl_xor(rs, 32);
      l += rs;
      union { unsigned u[2]; bf16x4 v; } a0, a1;
      a0.u[0] = cvtpk(p0[0], p0[1]); a0.u[1] = cvtpk(p0[2], p0[3]);
      a1.u[0] = cvtpk(p1[0], p1[1]); a1.u[1] = cvtpk(p1[2], p1[3]);
      const int lb = (s0 >> 3) + (hq >> 1);
      const char* vb = (const char*)Vs + (hq & 1) * 8;
      o0 = MFMA16(a0.v, *(const bf16x4*)(vb + r * 1024 + ((lb) ^ r) * 16), o0);
      o0 = MFMA16(a1.v, *(const bf16x4*)(vb + r * 1024 + ((lb + 2) ^ r) * 16), o0);
      o1 = MFMA16(a0.v, *(const bf16x4*)(vb + (r + 16) * 1024 + ((lb) ^ r) * 16), o1);
      o1 = MFMA16(a1.v, *(const bf16x4*)(vb + (r + 16) * 1024 + ((lb + 2) ^ r) * 16), o1);
    }
    // O ownership: d = r (o0) / 16+r (o1), q = t0 + 4*hq + j. l lives on lanes keyed by
    // r == q_rel (all 4 hq copies equal after the xor-reduce) -> shfl to fetch.
    const size_t ob = ((size_t)(bh >> 4) * 512) * 512 + (size_t)((bh & 15) * 32);
#pragma unroll
    for (int j = 0; j < 4; ++j) {
      const float li = 1.f / __shfl(l, 4 * hq + j);
      const size_t rowb = ob + (size_t)(t0 + 4 * hq + j) * 512;
      att[rowb + r]      = f2bf(o0[j] * li);
      att[rowb + 16 + r] = f2bf(o1[j] * li);
    }
  }
}

// ---------------- launcher ----------------
extern "C" void kernel_launch(void* const* d_in, const int* in_sizes, int n_in,
                              void* d_out, int out_size, void* d_ws, size_t ws_size,
                              hipStream_t stream)
{
  const float* x   = (const float*)d_in[0];
  const float* Wq  = (const float*)d_in[1];
  const float* Wk  = (const float*)d_in[2];
  const float* Wv  = (const float*)d_in[3];
  const float* Wp  = (const float*)d_in[4];
  const float* bp  = (const float*)d_in[5];
  const float* W1  = (const float*)d_in[6];
  const float* b1  = (const float*)d_in[7];
  const float* W2  = (const float*)d_in[8];
  const float* b2  = (const float*)d_in[9];
  const float* g1  = (const float*)d_in[10];
  const float* bb1 = (const float*)d_in[11];
  const float* g2  = (const float*)d_in[12];
  const float* bb2 = (const float*)d_in[13];
  float* out = (float*)d_out;

  char* ws = (char*)d_ws;
  // layout (bytes):
  unsigned short* h    = (unsigned short*)(ws);               // 32 MB (h, then reused as h2)
  unsigned short* wqkv = (unsigned short*)(ws + 33554432);    // 1.5 MB (1536 x 512)
  unsigned short* wp   = (unsigned short*)(ws + 35127296);    // 0.5 MB (512 x 512)
  unsigned short* w1   = (unsigned short*)(ws + 35651584);    // 2 MB (2048 x 512)
  unsigned short* w2   = (unsigned short*)(ws + 37748736);    // 2 MB (512 x 2048)
  unsigned short* qk   = (unsigned short*)(ws + 39845888);    // 64 MB: Q then K [B][H][T][D]
  unsigned short* vt   = qk + (size_t)2 * 16777216;           // 32 MB: V^T [B][H][D][T]
  unsigned short* att  = vt + 16777216;                       // 32 MB: attn out / V-natural
  unsigned short* vnat = att;                                 // V [B][H][T][D] staging
  unsigned short* mid  = qk;                                  // 128 MB alias over qk+vt+att
  if (ws_size < 174063616) return;  // insufficient workspace -> visible failure

  prep_qkv_w<<<384, 256, 0, stream>>>(Wq, Wk, Wv, wqkv);
  transpose_cast<<<64, 256, 0, stream>>>(Wp, wp, 512, 512);
  transpose_cast<<<256, 256, 0, stream>>>(W1, w1, 512, 2048);
  transpose_cast<<<256, 256, 0, stream>>>(W2, w2, 2048, 512);

  ln_kernel<<<8192, 256, 0, stream>>>(x, g1, bb1, h);

  qkv_gemm<<<3072, 256, 0, stream>>>(h, wqkv, 1536, 512, 12, qk, vnat);

  vt_kernel<<<8192, 256, 0, stream>>>(vnat, vt);

  attn_kernel<<<1024, 512, 0, stream>>>(qk, qk + 16777216, vt, att);

  proj_gemm<<<1024, 256, 0, stream>>>(att, wp, 512, 512, 4, out, bp, x);

  ln_kernel<<<8192, 256, 0, stream>>>(out, g2, bb2, h);

  ffn1_gemm<<<4096, 256, 0, stream>>>(h, w1, 2048, 512, 16, mid, b1);

  ffn2_gemm<<<1024, 256, 0, stream>>>(mid, w2, 512, 2048, 4, out, b2, out);
}

// Round 14
// 371.634 us; speedup vs baseline: 1.0993x; 1.0234x over previous
//
#include <hip/hip_runtime.h>
#include <stdint.h>

// Transformer block: B=64 T=512 C=512 H=16 D=32, FF=2048. fp32 in/out, bf16 MFMA inside.

typedef __attribute__((ext_vector_type(8))) short bf16x8;
typedef __attribute__((ext_vector_type(4))) short bf16x4;
typedef __attribute__((ext_vector_type(4))) float f32x4;

__device__ __forceinline__ unsigned short f2bf(float x) {
  union { float f; unsigned u; } v; v.f = x;
  unsigned r = v.u + 0x7fff + ((v.u >> 16) & 1);   // RNE
  return (unsigned short)(r >> 16);
}

#if __has_builtin(__builtin_amdgcn_exp2f)
__device__ __forceinline__ float exp2fast(float x) { return __builtin_amdgcn_exp2f(x); }
#else
__device__ __forceinline__ float exp2fast(float x) { return exp2f(x); }
#endif

// v_cvt_pk_bf16_f32: lo -> bits[15:0], hi -> bits[31:16] (RNE). No builtin on gfx950.
__device__ __forceinline__ unsigned cvtpk(float lo, float hi) {
  unsigned r; asm("v_cvt_pk_bf16_f32 %0, %1, %2" : "=v"(r) : "v"(lo), "v"(hi)); return r;
}

__device__ __forceinline__ f32x4 MFMA32(bf16x8 a, bf16x8 b, f32x4 c) {
  return __builtin_amdgcn_mfma_f32_16x16x32_bf16(a, b, c, 0, 0, 0);
}

#if __has_builtin(__builtin_amdgcn_mfma_f32_16x16x16bf16_1k)
__device__ __forceinline__ f32x4 MFMA16(bf16x4 a, bf16x4 b, f32x4 c) {
  return __builtin_amdgcn_mfma_f32_16x16x16bf16_1k(a, b, c, 0, 0, 0);
}
#else
__device__ __forceinline__ f32x4 MFMA16(bf16x4 a, bf16x4 b, f32x4 c) {
  f32x4 d;
  asm volatile("v_mfma_f32_16x16x16_bf16 %0, %1, %2, %3\n\ts_nop 7\n\ts_nop 3"
               : "=v"(d) : "v"(a), "v"(b), "v"(c));
  return d;
}
#endif

// global -> LDS direct copy, 16B per lane. LDS dest must be wave-uniform base;
// HW writes base + lane*16. Global src is per-lane.
__device__ __forceinline__ void gload_lds16(const void* g, void* l) {
  __builtin_amdgcn_global_load_lds(
      (const __attribute__((address_space(1))) unsigned int*)(uintptr_t)g,
      (__attribute__((address_space(3))) unsigned int*)(unsigned)(uintptr_t)l,
      16, 0, 0);
}

// ---------------- merged weight prep (one launch, 960 blocks) ----------------
// b in [0,384):   wqkv[n][k] = W{q,k,v}[h][k][d], n = q*512 + h*32 + d
// b in [384,448): wp  = Wp^T   (512 x 512)
// b in [448,704): w1  = W1^T   (2048 x 512)
// b in [704,960): w2  = W2^T   (512 x 2048)
__device__ __forceinline__ void transpose_body(
    const float* __restrict__ src, unsigned short* __restrict__ dst,
    int Kd, int Nd, int blk, float* tile /* 64*65 */)
{
  const int nk = Kd >> 6;
  const int kt = (blk % nk) << 6, nt = (blk / nk) << 6;
  const int t = threadIdx.x;
  const int rr = t >> 2, ch = (t & 3) << 4;  // read: k-row, 16-float chunk
  const float* sp = src + (size_t)(kt + rr) * Nd + nt + ch;
  float* dp = &tile[rr * 65 + ch];
#pragma unroll
  for (int c = 0; c < 4; ++c) {
    float4 v = *(const float4*)(sp + c * 4);
    dp[c * 4 + 0] = v.x; dp[c * 4 + 1] = v.y; dp[c * 4 + 2] = v.z; dp[c * 4 + 3] = v.w;
  }
  __syncthreads();
  const int nn = t >> 2, c2 = (t & 3) << 4;  // write: n-row, 16 k-elems
  bf16x8 o0, o1;
#pragma unroll
  for (int j = 0; j < 8; ++j) {
    o0[j] = (short)f2bf(tile[(c2 + j) * 65 + nn]);
    o1[j] = (short)f2bf(tile[(c2 + 8 + j) * 65 + nn]);
  }
  unsigned short* op = dst + (size_t)(nt + nn) * Kd + kt + c2;
  *(bf16x8*)(op) = o0;
  *(bf16x8*)(op + 8) = o1;
}

__global__ __launch_bounds__(256) void prep_all(
    const float* __restrict__ Wq, const float* __restrict__ Wk,
    const float* __restrict__ Wv, const float* __restrict__ Wp,
    const float* __restrict__ W1, const float* __restrict__ W2,
    unsigned short* __restrict__ wqkv, unsigned short* __restrict__ wp,
    unsigned short* __restrict__ w1, unsigned short* __restrict__ w2)
{
  __shared__ __align__(16) float tile[64 * 65];
  const int b = blockIdx.x;
  if (b < 384) {
    const int q = b / 128, hh = (b >> 3) & 15, kt = (b & 7) << 6;
    const float* W = (q == 0) ? Wq : ((q == 1) ? Wk : Wv);
    const int t = threadIdx.x;
    const int rr = t >> 2, ch = (t & 3) << 3;  // read: row, 8-float chunk (stride 33)
    const float* sp = W + ((size_t)hh * 512 + kt + rr) * 32 + ch;
    float4 v0 = *(const float4*)(sp), v1 = *(const float4*)(sp + 4);
    float* dp = &tile[rr * 33 + ch];
    dp[0] = v0.x; dp[1] = v0.y; dp[2] = v0.z; dp[3] = v0.w;
    dp[4] = v1.x; dp[5] = v1.y; dp[6] = v1.z; dp[7] = v1.w;
    __syncthreads();
    const int d = t >> 3, toct = (t & 7) << 3; // write: d-row, 8 k-elems
    bf16x8 o;
#pragma unroll
    for (int j = 0; j < 8; ++j) o[j] = (short)f2bf(tile[(toct + j) * 33 + d]);
    *(bf16x8*)(wqkv + ((size_t)q * 512 + hh * 32 + d) * 512 + kt + toct) = o;
  } else if (b < 448) {
    transpose_body(Wp, wp, 512, 512, b - 384, tile);
  } else if (b < 704) {
    transpose_body(W1, w1, 512, 2048, b - 448, tile);
  } else {
    transpose_body(W2, w2, 2048, 512, b - 704, tile);
  }
}

// ---------------- layernorm (fp32 in -> bf16 out), one wave per 512-row ----------------
__global__ __launch_bounds__(256) void ln_kernel(
    const float* __restrict__ x, const float* __restrict__ g,
    const float* __restrict__ b, unsigned short* __restrict__ out)
{
  const int lane = threadIdx.x & 63;
  const size_t row = (size_t)blockIdx.x * 4 + (threadIdx.x >> 6);
  const float* xp = x + row * 512 + lane * 8;
  float xv[8] __attribute__((aligned(16)));
  *(float4*)(xv)     = *(const float4*)(xp);
  *(float4*)(xv + 4) = *(const float4*)(xp + 4);
  float s = 0.f, s2 = 0.f;
#pragma unroll
  for (int j = 0; j < 8; ++j) { s += xv[j]; s2 += xv[j] * xv[j]; }
#pragma unroll
  for (int m = 1; m < 64; m <<= 1) { s += __shfl_xor(s, m); s2 += __shfl_xor(s2, m); }
  float mean = s * (1.f / 512.f);
  float rstd = rsqrtf(fmaxf(s2 * (1.f / 512.f) - mean * mean, 0.f) + 1e-5f);
  float gv[8] __attribute__((aligned(16))), bv[8] __attribute__((aligned(16)));
  *(float4*)(gv)     = *(const float4*)(g + lane * 8);
  *(float4*)(gv + 4) = *(const float4*)(g + lane * 8 + 4);
  *(float4*)(bv)     = *(const float4*)(b + lane * 8);
  *(float4*)(bv + 4) = *(const float4*)(b + lane * 8 + 4);
  bf16x8 o;
#pragma unroll
  for (int j = 0; j < 8; ++j) o[j] = (short)f2bf((xv[j] - mean) * rstd * gv[j] + bv[j]);
  *(bf16x8*)(out + row * 512 + lane * 8) = o;
}

// ---------------- V transpose: [B][H][T][D] -> [B][H][D][T], LDS-tiled ----------------
__global__ __launch_bounds__(256) void vt_kernel(
    const unsigned short* __restrict__ vnat, unsigned short* __restrict__ vt)
{
  __shared__ unsigned short tile[64 * 36];   // 64 t-rows x 32 d, padded to 36
  const int bh = blockIdx.x >> 3, tt = (blockIdx.x & 7) << 6;
  const int tid = threadIdx.x;
  const int rr = tid >> 2, ch = tid & 3;     // read: (t-row, 8-elem d-chunk)
  bf16x8 v = *(const bf16x8*)(vnat + ((size_t)bh * 512 + tt + rr) * 32 + ch * 8);
  unsigned short* dst = &tile[rr * 36 + ch * 8];
#pragma unroll
  for (int j = 0; j < 8; ++j) dst[j] = (unsigned short)v[j];
  __syncthreads();
  const int d = tid >> 3, toct = (tid & 7) << 3;  // write: (d-row, 8-elem t-chunk)
  union { unsigned short s[8]; bf16x8 v8; } o;
#pragma unroll
  for (int j = 0; j < 8; ++j) o.s[j] = tile[(toct + j) * 36 + d];
  *(bf16x8*)(vt + ((size_t)bh * 32 + d) * 512 + tt + toct) = o.v8;
}

// ---------------- m97-structure 128x128 GEMM: C = A(MxK,bf16) * Bt(NxK,bf16)^T -----
// 4 waves (2x2), per-wave C 64x64, BK=64, SINGLE-buffered 32KB LDS, ~3 blocks/CU.
// TLP hides stalls (m114); no manual waits/setprio/sched pinning (m141 lesson).
// 16B-chunk XOR swizzle on global src + same XOR on ds_read (G21); 0 bank conflicts.
// MODE 1: QKV scatter (Q,K -> obf [2][B][H][T][D], Q scaled; V -> vout natural)
// MODE 2: out fp32 = acc + bias[col] + resid[row*N+col]
// MODE 3: out bf16 = relu(acc + bias[col])
template <int MODE>
__device__ __forceinline__ void gemm128_body(
    const unsigned short* __restrict__ A, const unsigned short* __restrict__ Bt,
    int N, int K, int nby,
    unsigned short* __restrict__ obf, float* __restrict__ of32,
    const float* __restrict__ bias, const float* __restrict__ resid,
    unsigned short* __restrict__ vout)
{
  __shared__ __align__(16) unsigned short As[128 * 64];
  __shared__ __align__(16) unsigned short Bs[128 * 64];
  const int tid = threadIdx.x, lane = tid & 63, wid = tid >> 6;  // 4 waves
  const int wr = wid >> 1, wc = wid & 1;
  const int r = lane & 15, hq = lane >> 4;

  // XCD-aware bijective swizzle (all grids % 8 == 0), row-major decode
  const int qq = gridDim.x >> 3;
  const int swz = (blockIdx.x & 7) * qq + (blockIdx.x >> 3);
  const int bx = swz / nby, by = swz - bx * nby;
  const int brow = bx << 7, bcol = by << 7;
  const int nkt = K >> 6;

  const int srow = wid * 8 + (lane >> 3);
  const int schunk = ((lane & 7) ^ ((lane >> 3) & 7)) * 8;
  const unsigned short* Abase = A + (size_t)(brow + srow) * K + schunk;
  const unsigned short* Bbase = Bt + (size_t)(bcol + srow) * K + schunk;

  // ds_read addressing: byte = row*128 + ((chunk ^ (row&7))*16), chunk = kk*4+hq
  const int x0 = (hq ^ (r & 7)) * 16;
  const int x1 = ((4 + hq) ^ (r & 7)) * 16;
  const int abase = (wr * 64 + r) * 128;
  const int bbase = (wc * 64 + r) * 128;

  f32x4 acc[4][4] = {};

  for (int t = 0; t < nkt; ++t) {
    {
      const unsigned short* as_ = Abase + t * 64;
      const unsigned short* bs_ = Bbase + t * 64;
      char* al_ = (char*)As + wid * 1024;
      char* bl_ = (char*)Bs + wid * 1024;
#pragma unroll
      for (int g = 0; g < 4; ++g) {
        gload_lds16(as_ + (size_t)g * 32 * K, al_ + g * 4096);
        gload_lds16(bs_ + (size_t)g * 32 * K, bl_ + g * 4096);
      }
    }
    __syncthreads();
    bf16x8 bf[4][2];
#pragma unroll
    for (int n = 0; n < 4; ++n) {
      bf[n][0] = *(const bf16x8*)((const char*)Bs + bbase + n * 2048 + x0);
      bf[n][1] = *(const bf16x8*)((const char*)Bs + bbase + n * 2048 + x1);
    }
#pragma unroll
    for (int m = 0; m < 4; ++m) {
      const bf16x8 a0 = *(const bf16x8*)((const char*)As + abase + m * 2048 + x0);
      const bf16x8 a1 = *(const bf16x8*)((const char*)As + abase + m * 2048 + x1);
#pragma unroll
      for (int n = 0; n < 4; ++n) {
        acc[m][n] = MFMA32(a0, bf[n][0], acc[m][n]);
        acc[m][n] = MFMA32(a1, bf[n][1], acc[m][n]);
      }
    }
    __syncthreads();
  }

#pragma unroll
  for (int m = 0; m < 4; ++m)
#pragma unroll
    for (int n = 0; n < 4; ++n) {
      const int row0 = brow + wr * 64 + m * 16 + hq * 4;
      const int col = bcol + wc * 64 + n * 16 + r;
#pragma unroll
      for (int q2 = 0; q2 < 4; ++q2) {
        const int row = row0 + q2;
        float v = acc[m][n][q2];
        if (MODE == 1) {
          const int which = col >> 9, hh = (col >> 5) & 15, dd = col & 31;
          const int bb = row >> 9, tt = row & 511;
          const size_t off = ((((size_t)bb) * 16 + hh) * 512 + tt) * 32 + dd;
          if (which < 2) {
            if (which == 0) v *= 0.25503521f;  // (1/sqrt(32)) * log2(e)
            obf[(size_t)which * 16777216 + off] = f2bf(v);
          } else
            vout[off] = f2bf(v);
        } else if (MODE == 2) {
          v += bias[col] + resid[(size_t)row * N + col];
          of32[(size_t)row * N + col] = v;
        } else if (MODE == 3) {
          v = fmaxf(v + bias[col], 0.f);
          obf[(size_t)row * N + col] = f2bf(v);
        }
      }
    }
}

// distinct names per call site for rocprof attribution
__global__ __launch_bounds__(256, 3) void qkv_gemm(
    const unsigned short* __restrict__ A, const unsigned short* __restrict__ Bt,
    int N, int K, int nby, unsigned short* __restrict__ obf,
    unsigned short* __restrict__ vout)
{ gemm128_body<1>(A, Bt, N, K, nby, obf, nullptr, nullptr, nullptr, vout); }

__global__ __launch_bounds__(256, 3) void proj_gemm(
    const unsigned short* __restrict__ A, const unsigned short* __restrict__ Bt,
    int N, int K, int nby, float* __restrict__ of32,
    const float* __restrict__ bias, const float* __restrict__ resid)
{ gemm128_body<2>(A, Bt, N, K, nby, nullptr, of32, bias, resid, nullptr); }

__global__ __launch_bounds__(256, 3) void ffn1_gemm(
    const unsigned short* __restrict__ A, const unsigned short* __restrict__ Bt,
    int N, int K, int nby, unsigned short* __restrict__ obf,
    const float* __restrict__ bias)
{ gemm128_body<3>(A, Bt, N, K, nby, obf, nullptr, bias, nullptr, nullptr); }

__global__ __launch_bounds__(256, 3) void ffn2_gemm(
    const unsigned short* __restrict__ A, const unsigned short* __restrict__ Bt,
    int N, int K, int nby, float* __restrict__ of32,
    const float* __restrict__ bias, const float* __restrict__ resid)
{ gemm128_body<2>(A, Bt, N, K, nby, nullptr, of32, bias, resid, nullptr); }

// ---------------- causal attention: one block per (b,h), 8 waves ----------------
// (byte-for-byte the round-12 PASSING version: linear K staging, MFMA16 PV)
// Swapped QK^T: S^T = mfma(K_frag, Q_frag) so each lane owns one q-column with
// keys lane-local (k = 4*hq + j per 16-key tile). Softmax: in-lane tree + 2 shfl_xor.
// P feeds PV (16x16x16 MFMA) directly via cvt_pk -> no LDS round-trip.
// Scores arrive pre-scaled by (1/sqrt(32))*log2(e); exp = v_exp_f32 (2^x).
// Qb,Kb: [B][H][T][D] bf16 ; Vt: [B][H][D][T] bf16 ; att: [B*T][512] bf16 (col h*32+d)
__global__ __launch_bounds__(512, 4) void attn_kernel(
    const unsigned short* __restrict__ Qb, const unsigned short* __restrict__ Kb,
    const unsigned short* __restrict__ Vt, unsigned short* __restrict__ att)
{
  __shared__ __align__(16) unsigned short Ks[512 * 32];  // 32 KB, linear [t][d]
  __shared__ __align__(16) unsigned short Vs[32 * 512];  // 32 KB, [d][t], 16B-blk ^ (d&15)
  const int tid = threadIdx.x, lane = tid & 63, wid = tid >> 6;
  const int bh = blockIdx.x;
  const int r = lane & 15, hq = lane >> 4;
  const unsigned short* Kg = Kb + (size_t)bh * (512 * 32);
  const unsigned short* Vg = Vt + (size_t)bh * (32 * 512);
#pragma unroll
  for (int it = 0; it < 4; ++it) {
    const int c = it * 512 + tid;
    gload_lds16(Kg + c * 8, (char*)Ks + (it * 512 + wid * 64) * 16);
    const int d = c >> 6, sb = c & 63;
    gload_lds16(Vg + d * 512 + (sb ^ (d & 15)) * 8, (char*)Vs + (it * 512 + wid * 64) * 16);
  }
  __syncthreads();

  const f32x4 z = {0.f, 0.f, 0.f, 0.f};
  for (int p = 0; p < 4; ++p) {
    // balanced triangular tile pairing: waves get tiles {w, 15-w, 16+w, 31-w}
    const int t0 = (((p >> 1) << 4) + ((p & 1) ? 15 - wid : wid)) << 4;
    const bf16x8 qf = *(const bf16x8*)(Qb + ((size_t)bh * 512 + t0 + r) * 32 + hq * 8);
    f32x4 o0 = z, o1 = z;
    float m = -1e30f, l = 0.f;
    const int s0m = t0 & ~31;
    for (int s0 = 0; s0 <= s0m; s0 += 32) {
      f32x4 st0 = MFMA32(*(const bf16x8*)((const char*)Ks + (s0 + r) * 64 + hq * 16), qf, z);
      f32x4 st1 = MFMA32(*(const bf16x8*)((const char*)Ks + (s0 + 16 + r) * 64 + hq * 16), qf, z);
      if (s0 == s0m) {                       // only the diagonal chunk needs masking
        const int qq = t0 + r;
#pragma unroll
        for (int j = 0; j < 4; ++j) {
          if (s0 + 4 * hq + j > qq)      st0[j] = -1e30f;
          if (s0 + 16 + 4 * hq + j > qq) st1[j] = -1e30f;
        }
      }
      float mx = fmaxf(fmaxf(fmaxf(st0[0], st0[1]), fmaxf(st0[2], st0[3])),
                       fmaxf(fmaxf(st1[0], st1[1]), fmaxf(st1[2], st1[3])));
      mx = fmaxf(mx, __shfl_xor(mx, 16));
      mx = fmaxf(mx, __shfl_xor(mx, 32));
      if (!__all(mx <= m + 8.f)) {           // defer-max (T13), THR=8 in log2 domain
        const float mn = fmaxf(m, mx);
        const float f = exp2fast(m - mn);
        m = mn; l *= f; o0 *= f; o1 *= f;
      }
      float p0[4], p1[4];
#pragma unroll
      for (int j = 0; j < 4; ++j) {
        p0[j] = exp2fast(st0[j] - m);
        p1[j] = exp2fast(st1[j] - m);
      }
      float rs = ((p0[0] + p0[1]) + (p0[2] + p0[3])) + ((p1[0] + p1[1]) + (p1[2] + p1[3]));
      rs += __shfl_xor(rs, 16);
      rs += __shfl_xor(rs, 32);
      l += rs;
      union { unsigned u[2]; bf16x4 v; } a0, a1;
      a0.u[0] = cvtpk(p0[0], p0[1]); a0.u[1] = cvtpk(p0[2], p0[3]);
      a1.u[0] = cvtpk(p1[0], p1[1]); a1.u[1] = cvtpk(p1[2], p1[3]);
      const int lb = (s0 >> 3) + (hq >> 1);
      const char* vb = (const char*)Vs + (hq & 1) * 8;
      o0 = MFMA16(a0.v, *(const bf16x4*)(vb + r * 1024 + ((lb) ^ r) * 16), o0);
      o0 = MFMA16(a1.v, *(const bf16x4*)(vb + r * 1024 + ((lb + 2) ^ r) * 16), o0);
      o1 = MFMA16(a0.v, *(const bf16x4*)(vb + (r + 16) * 1024 + ((lb) ^ r) * 16), o1);
      o1 = MFMA16(a1.v, *(const bf16x4*)(vb + (r + 16) * 1024 + ((lb + 2) ^ r) * 16), o1);
    }
    // O ownership: d = r (o0) / 16+r (o1), q = t0 + 4*hq + j. l lives on lanes keyed by
    // r == q_rel (all 4 hq copies equal after the xor-reduce) -> shfl to fetch.
    const size_t ob = ((size_t)(bh >> 4) * 512) * 512 + (size_t)((bh & 15) * 32);
#pragma unroll
    for (int j = 0; j < 4; ++j) {
      const float li = 1.f / __shfl(l, 4 * hq + j);
      const size_t rowb = ob + (size_t)(t0 + 4 * hq + j) * 512;
      att[rowb + r]      = f2bf(o0[j] * li);
      att[rowb + 16 + r] = f2bf(o1[j] * li);
    }
  }
}

// ---------------- launcher ----------------
extern "C" void kernel_launch(void* const* d_in, const int* in_sizes, int n_in,
                              void* d_out, int out_size, void* d_ws, size_t ws_size,
                              hipStream_t stream)
{
  const float* x   = (const float*)d_in[0];
  const float* Wq  = (const float*)d_in[1];
  const float* Wk  = (const float*)d_in[2];
  const float* Wv  = (const float*)d_in[3];
  const float* Wp  = (const float*)d_in[4];
  const float* bp  = (const float*)d_in[5];
  const float* W1  = (const float*)d_in[6];
  const float* b1  = (const float*)d_in[7];
  const float* W2  = (const float*)d_in[8];
  const float* b2  = (const float*)d_in[9];
  const float* g1  = (const float*)d_in[10];
  const float* bb1 = (const float*)d_in[11];
  const float* g2  = (const float*)d_in[12];
  const float* bb2 = (const float*)d_in[13];
  float* out = (float*)d_out;

  char* ws = (char*)d_ws;
  // layout (bytes):
  unsigned short* h    = (unsigned short*)(ws);               // 32 MB (h, then reused as h2)
  unsigned short* wqkv = (unsigned short*)(ws + 33554432);    // 1.5 MB (1536 x 512)
  unsigned short* wp   = (unsigned short*)(ws + 35127296);    // 0.5 MB (512 x 512)
  unsigned short* w1   = (unsigned short*)(ws + 35651584);    // 2 MB (2048 x 512)
  unsigned short* w2   = (unsigned short*)(ws + 37748736);    // 2 MB (512 x 2048)
  unsigned short* qk   = (unsigned short*)(ws + 39845888);    // 64 MB: Q then K [B][H][T][D]
  unsigned short* vt   = qk + (size_t)2 * 16777216;           // 32 MB: V^T [B][H][D][T]
  unsigned short* att  = vt + 16777216;                       // 32 MB: attn out / V-natural
  unsigned short* vnat = att;                                 // V [B][H][T][D] staging
  unsigned short* mid  = qk;                                  // 128 MB alias over qk+vt+att
  if (ws_size < 174063616) return;  // insufficient workspace -> visible failure

  prep_all<<<960, 256, 0, stream>>>(Wq, Wk, Wv, Wp, W1, W2, wqkv, wp, w1, w2);

  ln_kernel<<<8192, 256, 0, stream>>>(x, g1, bb1, h);

  qkv_gemm<<<3072, 256, 0, stream>>>(h, wqkv, 1536, 512, 12, qk, vnat);

  vt_kernel<<<8192, 256, 0, stream>>>(vnat, vt);

  attn_kernel<<<1024, 512, 0, stream>>>(qk, qk + 16777216, vt, att);

  proj_gemm<<<1024, 256, 0, stream>>>(att, wp, 512, 512, 4, out, bp, x);

  ln_kernel<<<8192, 256, 0, stream>>>(out, g2, bb2, h);

  ffn1_gemm<<<4096, 256, 0, stream>>>(h, w1, 2048, 512, 16, mid, b1);

  ffn2_gemm<<<1024, 256, 0, stream>>>(mid, w2, 512, 2048, 4, out, b2, out);
}

// Round 15
// 361.643 us; speedup vs baseline: 1.1297x; 1.0276x over previous
//
#include <hip/hip_runtime.h>
#include <stdint.h>

// Transformer block: B=64 T=512 C=512 H=16 D=32, FF=2048. fp32 in/out, bf16 MFMA inside.

typedef __attribute__((ext_vector_type(8))) short bf16x8;
typedef __attribute__((ext_vector_type(4))) short bf16x4;
typedef __attribute__((ext_vector_type(4))) float f32x4;

__device__ __forceinline__ unsigned short f2bf(float x) {
  union { float f; unsigned u; } v; v.f = x;
  unsigned r = v.u + 0x7fff + ((v.u >> 16) & 1);   // RNE
  return (unsigned short)(r >> 16);
}

#if __has_builtin(__builtin_amdgcn_exp2f)
__device__ __forceinline__ float exp2fast(float x) { return __builtin_amdgcn_exp2f(x); }
#else
__device__ __forceinline__ float exp2fast(float x) { return exp2f(x); }
#endif

// v_cvt_pk_bf16_f32: lo -> bits[15:0], hi -> bits[31:16] (RNE). No builtin on gfx950.
__device__ __forceinline__ unsigned cvtpk(float lo, float hi) {
  unsigned r; asm("v_cvt_pk_bf16_f32 %0, %1, %2" : "=v"(r) : "v"(lo), "v"(hi)); return r;
}

__device__ __forceinline__ f32x4 MFMA32(bf16x8 a, bf16x8 b, f32x4 c) {
  return __builtin_amdgcn_mfma_f32_16x16x32_bf16(a, b, c, 0, 0, 0);
}

#if __has_builtin(__builtin_amdgcn_mfma_f32_16x16x16bf16_1k)
__device__ __forceinline__ f32x4 MFMA16(bf16x4 a, bf16x4 b, f32x4 c) {
  return __builtin_amdgcn_mfma_f32_16x16x16bf16_1k(a, b, c, 0, 0, 0);
}
#else
__device__ __forceinline__ f32x4 MFMA16(bf16x4 a, bf16x4 b, f32x4 c) {
  f32x4 d;
  asm volatile("v_mfma_f32_16x16x16_bf16 %0, %1, %2, %3\n\ts_nop 7\n\ts_nop 3"
               : "=v"(d) : "v"(a), "v"(b), "v"(c));
  return d;
}
#endif

// global -> LDS direct copy, 16B per lane. LDS dest must be wave-uniform base;
// HW writes base + lane*16. Global src is per-lane.
__device__ __forceinline__ void gload_lds16(const void* g, void* l) {
  __builtin_amdgcn_global_load_lds(
      (const __attribute__((address_space(1))) unsigned int*)(uintptr_t)g,
      (__attribute__((address_space(3))) unsigned int*)(unsigned)(uintptr_t)l,
      16, 0, 0);
}

// ---------------- merged weight prep (one launch, 960 blocks) ----------------
// b in [0,384):   wqkv[n][k] = W{q,k,v}[h][k][d], n = q*512 + h*32 + d
// b in [384,448): wp  = Wp^T   (512 x 512)
// b in [448,704): w1  = W1^T   (2048 x 512)
// b in [704,960): w2  = W2^T   (512 x 2048)
__device__ __forceinline__ void transpose_body(
    const float* __restrict__ src, unsigned short* __restrict__ dst,
    int Kd, int Nd, int blk, float* tile /* 64*65 */)
{
  const int nk = Kd >> 6;
  const int kt = (blk % nk) << 6, nt = (blk / nk) << 6;
  const int t = threadIdx.x;
  const int rr = t >> 2, ch = (t & 3) << 4;  // read: k-row, 16-float chunk
  const float* sp = src + (size_t)(kt + rr) * Nd + nt + ch;
  float* dp = &tile[rr * 65 + ch];
#pragma unroll
  for (int c = 0; c < 4; ++c) {
    float4 v = *(const float4*)(sp + c * 4);
    dp[c * 4 + 0] = v.x; dp[c * 4 + 1] = v.y; dp[c * 4 + 2] = v.z; dp[c * 4 + 3] = v.w;
  }
  __syncthreads();
  const int nn = t >> 2, c2 = (t & 3) << 4;  // write: n-row, 16 k-elems
  bf16x8 o0, o1;
#pragma unroll
  for (int j = 0; j < 8; ++j) {
    o0[j] = (short)f2bf(tile[(c2 + j) * 65 + nn]);
    o1[j] = (short)f2bf(tile[(c2 + 8 + j) * 65 + nn]);
  }
  unsigned short* op = dst + (size_t)(nt + nn) * Kd + kt + c2;
  *(bf16x8*)(op) = o0;
  *(bf16x8*)(op + 8) = o1;
}

__global__ __launch_bounds__(256) void prep_all(
    const float* __restrict__ Wq, const float* __restrict__ Wk,
    const float* __restrict__ Wv, const float* __restrict__ Wp,
    const float* __restrict__ W1, const float* __restrict__ W2,
    unsigned short* __restrict__ wqkv, unsigned short* __restrict__ wp,
    unsigned short* __restrict__ w1, unsigned short* __restrict__ w2)
{
  __shared__ __align__(16) float tile[64 * 65];
  const int b = blockIdx.x;
  if (b < 384) {
    const int q = b / 128, hh = (b >> 3) & 15, kt = (b & 7) << 6;
    const float* W = (q == 0) ? Wq : ((q == 1) ? Wk : Wv);
    const int t = threadIdx.x;
    const int rr = t >> 2, ch = (t & 3) << 3;  // read: row, 8-float chunk (stride 33)
    const float* sp = W + ((size_t)hh * 512 + kt + rr) * 32 + ch;
    float4 v0 = *(const float4*)(sp), v1 = *(const float4*)(sp + 4);
    float* dp = &tile[rr * 33 + ch];
    dp[0] = v0.x; dp[1] = v0.y; dp[2] = v0.z; dp[3] = v0.w;
    dp[4] = v1.x; dp[5] = v1.y; dp[6] = v1.z; dp[7] = v1.w;
    __syncthreads();
    const int d = t >> 3, toct = (t & 7) << 3; // write: d-row, 8 k-elems
    bf16x8 o;
#pragma unroll
    for (int j = 0; j < 8; ++j) o[j] = (short)f2bf(tile[(toct + j) * 33 + d]);
    *(bf16x8*)(wqkv + ((size_t)q * 512 + hh * 32 + d) * 512 + kt + toct) = o;
  } else if (b < 448) {
    transpose_body(Wp, wp, 512, 512, b - 384, tile);
  } else if (b < 704) {
    transpose_body(W1, w1, 512, 2048, b - 448, tile);
  } else {
    transpose_body(W2, w2, 2048, 512, b - 704, tile);
  }
}

// ---------------- layernorm (fp32 in -> bf16 out), one wave per 512-row ----------------
__global__ __launch_bounds__(256) void ln_kernel(
    const float* __restrict__ x, const float* __restrict__ g,
    const float* __restrict__ b, unsigned short* __restrict__ out)
{
  const int lane = threadIdx.x & 63;
  const size_t row = (size_t)blockIdx.x * 4 + (threadIdx.x >> 6);
  const float* xp = x + row * 512 + lane * 8;
  float xv[8] __attribute__((aligned(16)));
  *(float4*)(xv)     = *(const float4*)(xp);
  *(float4*)(xv + 4) = *(const float4*)(xp + 4);
  float s = 0.f, s2 = 0.f;
#pragma unroll
  for (int j = 0; j < 8; ++j) { s += xv[j]; s2 += xv[j] * xv[j]; }
#pragma unroll
  for (int m = 1; m < 64; m <<= 1) { s += __shfl_xor(s, m); s2 += __shfl_xor(s2, m); }
  float mean = s * (1.f / 512.f);
  float rstd = rsqrtf(fmaxf(s2 * (1.f / 512.f) - mean * mean, 0.f) + 1e-5f);
  float gv[8] __attribute__((aligned(16))), bv[8] __attribute__((aligned(16)));
  *(float4*)(gv)     = *(const float4*)(g + lane * 8);
  *(float4*)(gv + 4) = *(const float4*)(g + lane * 8 + 4);
  *(float4*)(bv)     = *(const float4*)(b + lane * 8);
  *(float4*)(bv + 4) = *(const float4*)(b + lane * 8 + 4);
  bf16x8 o;
#pragma unroll
  for (int j = 0; j < 8; ++j) o[j] = (short)f2bf((xv[j] - mean) * rstd * gv[j] + bv[j]);
  *(bf16x8*)(out + row * 512 + lane * 8) = o;
}

// ---------------- m97-structure 128x128 GEMM: C = A(MxK,bf16) * Bt(NxK,bf16)^T -----
// 4 waves (2x2), per-wave C 64x64, BK=64, SINGLE-buffered 32KB LDS, ~3 blocks/CU.
// TLP hides stalls (m114); no manual waits/setprio/sched pinning (m141 lesson).
// 16B-chunk XOR swizzle on global src + same XOR on ds_read (G21); 0 bank conflicts.
// MODE 1: QKV. Q,K blocks scatter to obf [2][B][H][T][D] (Q scaled). V blocks
//         (bcol >= 1024) transpose in-LDS (buffer dead after K-loop) and write
//         vout = V^T [B][H][D][T] directly -- replaces the separate vt_kernel.
// MODE 2: out fp32 = acc + bias[col] + resid[row*N+col]
// MODE 3: out bf16 = relu(acc + bias[col])
template <int MODE>
__device__ __forceinline__ void gemm128_body(
    const unsigned short* __restrict__ A, const unsigned short* __restrict__ Bt,
    int N, int K, int nby,
    unsigned short* __restrict__ obf, float* __restrict__ of32,
    const float* __restrict__ bias, const float* __restrict__ resid,
    unsigned short* __restrict__ vout)
{
  __shared__ __align__(16) unsigned short SMEM[2 * 128 * 64];  // As | Bs (contiguous)
  unsigned short* Asm = SMEM;
  unsigned short* Bsm = SMEM + 128 * 64;
  const int tid = threadIdx.x, lane = tid & 63, wid = tid >> 6;  // 4 waves
  const int wr = wid >> 1, wc = wid & 1;
  const int r = lane & 15, hq = lane >> 4;

  // XCD-aware bijective swizzle (all grids % 8 == 0), row-major decode
  const int qq = gridDim.x >> 3;
  const int swz = (blockIdx.x & 7) * qq + (blockIdx.x >> 3);
  const int bx = swz / nby, by = swz - bx * nby;
  const int brow = bx << 7, bcol = by << 7;
  const int nkt = K >> 6;

  const int srow = wid * 8 + (lane >> 3);
  const int schunk = ((lane & 7) ^ ((lane >> 3) & 7)) * 8;
  const unsigned short* Abase = A + (size_t)(brow + srow) * K + schunk;
  const unsigned short* Bbase = Bt + (size_t)(bcol + srow) * K + schunk;

  // ds_read addressing: byte = row*128 + ((chunk ^ (row&7))*16), chunk = kk*4+hq
  const int x0 = (hq ^ (r & 7)) * 16;
  const int x1 = ((4 + hq) ^ (r & 7)) * 16;
  const int abase = (wr * 64 + r) * 128;
  const int bbase = (wc * 64 + r) * 128;

  f32x4 acc[4][4] = {};

  for (int t = 0; t < nkt; ++t) {
    {
      const unsigned short* as_ = Abase + t * 64;
      const unsigned short* bs_ = Bbase + t * 64;
      char* al_ = (char*)Asm + wid * 1024;
      char* bl_ = (char*)Bsm + wid * 1024;
#pragma unroll
      for (int g = 0; g < 4; ++g) {
        gload_lds16(as_ + (size_t)g * 32 * K, al_ + g * 4096);
        gload_lds16(bs_ + (size_t)g * 32 * K, bl_ + g * 4096);
      }
    }
    __syncthreads();
    bf16x8 bf[4][2];
#pragma unroll
    for (int n = 0; n < 4; ++n) {
      bf[n][0] = *(const bf16x8*)((const char*)Bsm + bbase + n * 2048 + x0);
      bf[n][1] = *(const bf16x8*)((const char*)Bsm + bbase + n * 2048 + x1);
    }
#pragma unroll
    for (int m = 0; m < 4; ++m) {
      const bf16x8 a0 = *(const bf16x8*)((const char*)Asm + abase + m * 2048 + x0);
      const bf16x8 a1 = *(const bf16x8*)((const char*)Asm + abase + m * 2048 + x1);
#pragma unroll
      for (int n = 0; n < 4; ++n) {
        acc[m][n] = MFMA32(a0, bf[n][0], acc[m][n]);
        acc[m][n] = MFMA32(a1, bf[n][1], acc[m][n]);
      }
    }
    __syncthreads();
  }

  if (MODE == 1 && bcol >= 1024) {
    // ---- V-block epilogue: transpose 128x128 C-tile via LDS (buffer is dead),
    //      two 64-col halves (wave pair wc==half owns the half's acc), then
    //      coalesced 16B stores into vout = V^T [B][H][D][T].
    const int bb = brow >> 9, tt0 = brow & 511;
    unsigned short* tile = SMEM;            // [64][132] u16 = 16.5KB < 32KB
#pragma unroll
    for (int half = 0; half < 2; ++half) {
      if (wc == half) {
#pragma unroll
        for (int m = 0; m < 4; ++m)
#pragma unroll
          for (int n = 0; n < 4; ++n) {
            const int lc = n * 16 + r;                    // 0..63 in half
            const int lr0 = wr * 64 + m * 16 + hq * 4;    // 0..127
#pragma unroll
            for (int q2 = 0; q2 < 4; ++q2)
              tile[lc * 132 + lr0 + q2] = f2bf(acc[m][n][q2]);
          }
      }
      __syncthreads();
#pragma unroll
      for (int i = 0; i < 4; ++i) {
        const int c2 = i * 16 + (tid >> 4);               // 0..63
        const int tc = (tid & 15) * 8;                    // 0..120
        const int gcol = bcol + half * 64 + c2;
        const int hh = (gcol >> 5) & 15, dd = gcol & 31;
        union { unsigned short s[8]; bf16x8 v8; } o;
#pragma unroll
        for (int j = 0; j < 8; ++j) o.s[j] = tile[c2 * 132 + tc + j];
        *(bf16x8*)(vout + (((size_t)bb * 16 + hh) * 32 + dd) * 512 + tt0 + tc) = o.v8;
      }
      __syncthreads();
    }
    return;
  }

#pragma unroll
  for (int m = 0; m < 4; ++m)
#pragma unroll
    for (int n = 0; n < 4; ++n) {
      const int row0 = brow + wr * 64 + m * 16 + hq * 4;
      const int col = bcol + wc * 64 + n * 16 + r;
#pragma unroll
      for (int q2 = 0; q2 < 4; ++q2) {
        const int row = row0 + q2;
        float v = acc[m][n][q2];
        if (MODE == 1) {
          const int which = col >> 9, hh = (col >> 5) & 15, dd = col & 31;
          const int bb = row >> 9, tt = row & 511;
          const size_t off = ((((size_t)bb) * 16 + hh) * 512 + tt) * 32 + dd;
          if (which == 0) v *= 0.25503521f;  // (1/sqrt(32)) * log2(e)
          obf[(size_t)which * 16777216 + off] = f2bf(v);
        } else if (MODE == 2) {
          v += bias[col] + resid[(size_t)row * N + col];
          of32[(size_t)row * N + col] = v;
        } else if (MODE == 3) {
          v = fmaxf(v + bias[col], 0.f);
          obf[(size_t)row * N + col] = f2bf(v);
        }
      }
    }
}

// distinct names per call site for rocprof attribution
__global__ __launch_bounds__(256, 3) void qkv_gemm(
    const unsigned short* __restrict__ A, const unsigned short* __restrict__ Bt,
    int N, int K, int nby, unsigned short* __restrict__ obf,
    unsigned short* __restrict__ vout)
{ gemm128_body<1>(A, Bt, N, K, nby, obf, nullptr, nullptr, nullptr, vout); }

__global__ __launch_bounds__(256, 3) void proj_gemm(
    const unsigned short* __restrict__ A, const unsigned short* __restrict__ Bt,
    int N, int K, int nby, float* __restrict__ of32,
    const float* __restrict__ bias, const float* __restrict__ resid)
{ gemm128_body<2>(A, Bt, N, K, nby, nullptr, of32, bias, resid, nullptr); }

__global__ __launch_bounds__(256, 3) void ffn1_gemm(
    const unsigned short* __restrict__ A, const unsigned short* __restrict__ Bt,
    int N, int K, int nby, unsigned short* __restrict__ obf,
    const float* __restrict__ bias)
{ gemm128_body<3>(A, Bt, N, K, nby, obf, nullptr, bias, nullptr, nullptr); }

__global__ __launch_bounds__(256, 3) void ffn2_gemm(
    const unsigned short* __restrict__ A, const unsigned short* __restrict__ Bt,
    int N, int K, int nby, float* __restrict__ of32,
    const float* __restrict__ bias, const float* __restrict__ resid)
{ gemm128_body<2>(A, Bt, N, K, nby, nullptr, of32, bias, resid, nullptr); }

// ---------------- causal attention: one block per (b,h), 8 waves ----------------
// (round-12 PASSING version: linear K staging, MFMA16 PV)
// Swapped QK^T: S^T = mfma(K_frag, Q_frag) so each lane owns one q-column with
// keys lane-local (k = 4*hq + j per 16-key tile). Softmax: in-lane tree + 2 shfl_xor.
// P feeds PV (16x16x16 MFMA) directly via cvt_pk -> no LDS round-trip.
// Scores arrive pre-scaled by (1/sqrt(32))*log2(e); exp = v_exp_f32 (2^x).
// Qb,Kb: [B][H][T][D] bf16 ; Vt: [B][H][D][T] bf16 ; att: [B*T][512] bf16 (col h*32+d)
__global__ __launch_bounds__(512, 4) void attn_kernel(
    const unsigned short* __restrict__ Qb, const unsigned short* __restrict__ Kb,
    const unsigned short* __restrict__ Vt, unsigned short* __restrict__ att)
{
  __shared__ __align__(16) unsigned short Ks[512 * 32];  // 32 KB, linear [t][d]
  __shared__ __align__(16) unsigned short Vs[32 * 512];  // 32 KB, [d][t], 16B-blk ^ (d&15)
  const int tid = threadIdx.x, lane = tid & 63, wid = tid >> 6;
  const int bh = blockIdx.x;
  const int r = lane & 15, hq = lane >> 4;
  const unsigned short* Kg = Kb + (size_t)bh * (512 * 32);
  const unsigned short* Vg = Vt + (size_t)bh * (32 * 512);
#pragma unroll
  for (int it = 0; it < 4; ++it) {
    const int c = it * 512 + tid;
    gload_lds16(Kg + c * 8, (char*)Ks + (it * 512 + wid * 64) * 16);
    const int d = c >> 6, sb = c & 63;
    gload_lds16(Vg + d * 512 + (sb ^ (d & 15)) * 8, (char*)Vs + (it * 512 + wid * 64) * 16);
  }
  __syncthreads();

  const f32x4 z = {0.f, 0.f, 0.f, 0.f};
  for (int p = 0; p < 4; ++p) {
    // balanced triangular tile pairing: waves get tiles {w, 15-w, 16+w, 31-w}
    const int t0 = (((p >> 1) << 4) + ((p & 1) ? 15 - wid : wid)) << 4;
    const bf16x8 qf = *(const bf16x8*)(Qb + ((size_t)bh * 512 + t0 + r) * 32 + hq * 8);
    f32x4 o0 = z, o1 = z;
    float m = -1e30f, l = 0.f;
    const int s0m = t0 & ~31;
    for (int s0 = 0; s0 <= s0m; s0 += 32) {
      f32x4 st0 = MFMA32(*(const bf16x8*)((const char*)Ks + (s0 + r) * 64 + hq * 16), qf, z);
      f32x4 st1 = MFMA32(*(const bf16x8*)((const char*)Ks + (s0 + 16 + r) * 64 + hq * 16), qf, z);
      if (s0 == s0m) {                       // only the diagonal chunk needs masking
        const int qq = t0 + r;
#pragma unroll
        for (int j = 0; j < 4; ++j) {
          if (s0 + 4 * hq + j > qq)      st0[j] = -1e30f;
          if (s0 + 16 + 4 * hq + j > qq) st1[j] = -1e30f;
        }
      }
      float mx = fmaxf(fmaxf(fmaxf(st0[0], st0[1]), fmaxf(st0[2], st0[3])),
                       fmaxf(fmaxf(st1[0], st1[1]), fmaxf(st1[2], st1[3])));
      mx = fmaxf(mx, __shfl_xor(mx, 16));
      mx = fmaxf(mx, __shfl_xor(mx, 32));
      if (!__all(mx <= m + 8.f)) {           // defer-max (T13), THR=8 in log2 domain
        const float mn = fmaxf(m, mx);
        const float f = exp2fast(m - mn);
        m = mn; l *= f; o0 *= f; o1 *= f;
      }
      float p0[4], p1[4];
#pragma unroll
      for (int j = 0; j < 4; ++j) {
        p0[j] = exp2fast(st0[j] - m);
        p1[j] = exp2fast(st1[j] - m);
      }
      float rs = ((p0[0] + p0[1]) + (p0[2] + p0[3])) + ((p1[0] + p1[1]) + (p1[2] + p1[3]));
      rs += __shfl_xor(rs, 16);
      rs += __shfl_xor(rs, 32);
      l += rs;
      union { unsigned u[2]; bf16x4 v; } a0, a1;
      a0.u[0] = cvtpk(p0[0], p0[1]); a0.u[1] = cvtpk(p0[2], p0[3]);
      a1.u[0] = cvtpk(p1[0], p1[1]); a1.u[1] = cvtpk(p1[2], p1[3]);
      const int lb = (s0 >> 3) + (hq >> 1);
      const char* vb = (const char*)Vs + (hq & 1) * 8;
      o0 = MFMA16(a0.v, *(const bf16x4*)(vb + r * 1024 + ((lb) ^ r) * 16), o0);
      o0 = MFMA16(a1.v, *(const bf16x4*)(vb + r * 1024 + ((lb + 2) ^ r) * 16), o0);
      o1 = MFMA16(a0.v, *(const bf16x4*)(vb + (r + 16) * 1024 + ((lb) ^ r) * 16), o1);
      o1 = MFMA16(a1.v, *(const bf16x4*)(vb + (r + 16) * 1024 + ((lb + 2) ^ r) * 16), o1);
    }
    // O ownership: d = r (o0) / 16+r (o1), q = t0 + 4*hq + j. l lives on lanes keyed by
    // r == q_rel (all 4 hq copies equal after the xor-reduce) -> shfl to fetch.
    const size_t ob = ((size_t)(bh >> 4) * 512) * 512 + (size_t)((bh & 15) * 32);
#pragma unroll
    for (int j = 0; j < 4; ++j) {
      const float li = 1.f / __shfl(l, 4 * hq + j);
      const size_t rowb = ob + (size_t)(t0 + 4 * hq + j) * 512;
      att[rowb + r]      = f2bf(o0[j] * li);
      att[rowb + 16 + r] = f2bf(o1[j] * li);
    }
  }
}

// ---------------- launcher ----------------
extern "C" void kernel_launch(void* const* d_in, const int* in_sizes, int n_in,
                              void* d_out, int out_size, void* d_ws, size_t ws_size,
                              hipStream_t stream)
{
  const float* x   = (const float*)d_in[0];
  const float* Wq  = (const float*)d_in[1];
  const float* Wk  = (const float*)d_in[2];
  const float* Wv  = (const float*)d_in[3];
  const float* Wp  = (const float*)d_in[4];
  const float* bp  = (const float*)d_in[5];
  const float* W1  = (const float*)d_in[6];
  const float* b1  = (const float*)d_in[7];
  const float* W2  = (const float*)d_in[8];
  const float* b2  = (const float*)d_in[9];
  const float* g1  = (const float*)d_in[10];
  const float* bb1 = (const float*)d_in[11];
  const float* g2  = (const float*)d_in[12];
  const float* bb2 = (const float*)d_in[13];
  float* out = (float*)d_out;

  char* ws = (char*)d_ws;
  // layout (bytes):
  unsigned short* h    = (unsigned short*)(ws);               // 32 MB (h, then reused as h2)
  unsigned short* wqkv = (unsigned short*)(ws + 33554432);    // 1.5 MB (1536 x 512)
  unsigned short* wp   = (unsigned short*)(ws + 35127296);    // 0.5 MB (512 x 512)
  unsigned short* w1   = (unsigned short*)(ws + 35651584);    // 2 MB (2048 x 512)
  unsigned short* w2   = (unsigned short*)(ws + 37748736);    // 2 MB (512 x 2048)
  unsigned short* qk   = (unsigned short*)(ws + 39845888);    // 64 MB: Q then K [B][H][T][D]
  unsigned short* vt   = qk + (size_t)2 * 16777216;           // 32 MB: V^T [B][H][D][T]
  unsigned short* att  = vt + 16777216;                       // 32 MB: attn out
  unsigned short* mid  = qk;                                  // 128 MB alias over qk+vt+att
  if (ws_size < 174063616) return;  // insufficient workspace -> visible failure

  prep_all<<<960, 256, 0, stream>>>(Wq, Wk, Wv, Wp, W1, W2, wqkv, wp, w1, w2);

  ln_kernel<<<8192, 256, 0, stream>>>(x, g1, bb1, h);

  qkv_gemm<<<3072, 256, 0, stream>>>(h, wqkv, 1536, 512, 12, qk, vt);

  attn_kernel<<<1024, 512, 0, stream>>>(qk, qk + 16777216, vt, att);

  proj_gemm<<<1024, 256, 0, stream>>>(att, wp, 512, 512, 4, out, bp, x);

  ln_kernel<<<8192, 256, 0, stream>>>(out, g2, bb2, h);

  ffn1_gemm<<<4096, 256, 0, stream>>>(h, w1, 2048, 512, 16, mid, b1);

  ffn2_gemm<<<1024, 256, 0, stream>>>(mid, w2, 512, 2048, 4, out, b2, out);
}